// Round 1
// baseline (833.836 us; speedup 1.0000x reference)
//
#include <hip/hip_runtime.h>
#include <hip/hip_bf16.h>

// Problem constants
#define BB 20
#define SS 500
#define DIMD 300
#define HIDH 600
#define QKD 128

// ---------------- LayerNorm + sequence shift ----------------
// nx[b,s,0:150]   = LN(x)[b,s-1,0:150]  (0 for s==0)
// nx[b,s,150:300] = LN(x)[b,s,150:300]
__global__ __launch_bounds__(64)
void ln_shift_kernel(const float* __restrict__ x, const float* __restrict__ g,
                     const float* __restrict__ be, float* __restrict__ nx) {
    int bs = blockIdx.x;            // b*500 + s
    int s = bs % SS;
    int t = threadIdx.x;
    const float* xr = x + (long)bs * DIMD;
    float sum = 0.f, sq = 0.f;
    for (int d = t; d < DIMD; d += 64) { float v = xr[d]; sum += v; sq += v * v; }
    for (int off = 1; off < 64; off <<= 1) {
        sum += __shfl_xor(sum, off);
        sq  += __shfl_xor(sq, off);
    }
    float mean = sum * (1.f / DIMD);
    float var  = sq * (1.f / DIMD) - mean * mean;
    float rstd = rsqrtf(var + 1e-5f);
    for (int d = t; d < DIMD; d += 64) {
        float nv = (xr[d] - mean) * rstd * g[d] + be[d];
        if (d < DIMD / 2) {
            if (s < SS - 1) nx[(long)(bs + 1) * DIMD + d] = nv;
        } else {
            nx[(long)bs * DIMD + d] = nv;
        }
    }
    if (s == 0)
        for (int d = t; d < DIMD / 2; d += 64) nx[(long)bs * DIMD + d] = 0.f;
}

// ---------------- Epilogue functors ----------------
struct EpiSiluBias {
    const float* bias;
    __device__ float operator()(float acc, int b, int m, int n) const {
        float v = acc + bias[n];
        return v / (1.f + expf(-v));      // silu
    }
};
struct EpiAttn {
    const float* bias;   // 500x500 T5 bias
    const float* mask;   // 500x500
    __device__ float operator()(float acc, int b, int m, int n) const {
        float s = (acc + bias[m * SS + n]) * (1.f / (float)SS);
        s = fmaxf(s, 0.f);
        return s * s * mask[m * SS + n];
    }
};
struct EpiGate {
    const float* h;      // (B*S,1200), gate at col 600+
    const int* counts;   // (B,100,120)
    const int* t2;       // (B,)
    __device__ float operator()(float acc, int b, int m, int n) const {
        float g = h[((long)(b * SS + m)) * 1200 + 600 + n];
        int c = counts[(b * 100 + m / 5) * 120 + n / 5];
        float bv = (c >= t2[b]) ? 1.f : 0.25f;
        float p = ((m % 5) == 4 || (n % 5) == 4) ? 0.f : 1.f;
        return acc * g * bv * p;
    }
};
struct EpiOut {
    const float* bout;
    const float* x;
    __device__ float operator()(float acc, int b, int m, int n) const {
        return acc + bout[n] + x[(long)m * DIMD + n];
    }
};

// ---------------- Generic 64x64 tiled fp32 GEMM ----------------
// C[M,N] = A[M,K] * B[K,N]  (TRANSB: B stored [N,K], ldb = row stride of that)
template<bool TRANSB, class Epi>
__global__ __launch_bounds__(256)
void gemm_tile(const float* __restrict__ A, const float* __restrict__ B,
               float* __restrict__ C,
               int M, int N, int K, int lda, int ldb, int ldc,
               long sA, long sB, long sC, Epi epi) {
    int bz = blockIdx.z;
    A += (long)bz * sA; B += (long)bz * sB; C += (long)bz * sC;
    int m0 = blockIdx.y * 64;
    int n0 = blockIdx.x * 64;
    int t = threadIdx.x;
    int tx = t & 15, ty = t >> 4;

    __shared__ float As[16][68];   // [k][m], 68 keeps float4 alignment + spreads banks
    __shared__ float Bs[16][68];   // [k][n]

    float acc[4][4] = {};

    for (int k0 = 0; k0 < K; k0 += 16) {
        // A tile: 64 rows x 16 k, float4 along k  (all K used are %4==0)
        {
            int row = t >> 2, kb = (t & 3) << 2;
            float4 av = make_float4(0.f, 0.f, 0.f, 0.f);
            if (m0 + row < M && k0 + kb < K)
                av = *(const float4*)(A + (long)(m0 + row) * lda + k0 + kb);
            As[kb + 0][row] = av.x; As[kb + 1][row] = av.y;
            As[kb + 2][row] = av.z; As[kb + 3][row] = av.w;
        }
        if (!TRANSB) {
            int kr = t >> 4, nb = (t & 15) << 2;
            float4 bv = make_float4(0.f, 0.f, 0.f, 0.f);
            if (k0 + kr < K && n0 + nb < N)
                bv = *(const float4*)(B + (long)(k0 + kr) * ldb + n0 + nb);
            *(float4*)(&Bs[kr][nb]) = bv;
        } else {
            int j = t >> 2, kb = (t & 3) << 2;
            float4 bv = make_float4(0.f, 0.f, 0.f, 0.f);
            if (n0 + j < N && k0 + kb < K)
                bv = *(const float4*)(B + (long)(n0 + j) * ldb + k0 + kb);
            Bs[kb + 0][j] = bv.x; Bs[kb + 1][j] = bv.y;
            Bs[kb + 2][j] = bv.z; Bs[kb + 3][j] = bv.w;
        }
        __syncthreads();
#pragma unroll
        for (int kk = 0; kk < 16; ++kk) {
            float4 a = *(const float4*)(&As[kk][ty << 2]);
            float4 bq = *(const float4*)(&Bs[kk][tx << 2]);
            float av4[4] = {a.x, a.y, a.z, a.w};
            float bv4[4] = {bq.x, bq.y, bq.z, bq.w};
#pragma unroll
            for (int i = 0; i < 4; ++i)
#pragma unroll
                for (int j = 0; j < 4; ++j)
                    acc[i][j] = fmaf(av4[i], bv4[j], acc[i][j]);
        }
        __syncthreads();
    }
#pragma unroll
    for (int i = 0; i < 4; ++i) {
        int gm = m0 + (ty << 2) + i;
        if (gm >= M) continue;
#pragma unroll
        for (int j = 0; j < 4; ++j) {
            int gn = n0 + (tx << 2) + j;
            if (gn >= N) continue;
            C[(long)gm * ldc + gn] = epi(acc[i][j], bz, gm, gn);
        }
    }
}

// ---------------- qk -> rotary q,k ----------------
__global__ __launch_bounds__(128)
void rotary_kernel(const float* __restrict__ qk, const float* __restrict__ gamma,
                   const float* __restrict__ beta, float* __restrict__ q,
                   float* __restrict__ k) {
    int bs = blockIdx.x;
    int s = bs % SS;
    int d = threadIdx.x;
    float v = qk[(long)bs * QKD + d];
    float qp = v * gamma[d] + beta[d];
    float kp = v * gamma[QKD + d] + beta[QKD + d];
    float qpart = __shfl_xor(qp, 1);
    float kpart = __shfl_xor(kp, 1);
    float qo = qp, ko = kp;
    if (d < 32) {
        float inv = expf(-(float)(d & ~1) * (logf(10000.f) / 32.f));
        float ang = (float)s * inv;
        float c = cosf(ang), sn = sinf(ang);
        float qr = (d & 1) ? qpart : -qpart;
        float kr = (d & 1) ? kpart : -kpart;
        qo = qp * c + qr * sn;
        ko = kp * c + kr * sn;
    }
    q[(long)bs * QKD + d] = qo;
    k[(long)bs * QKD + d] = ko;
}

// ---------------- T5 relative bias table (500x500) ----------------
__global__ void t5bias_kernel(const float* __restrict__ emb, float* __restrict__ bias) {
    int id = blockIdx.x * 256 + threadIdx.x;
    if (id >= SS * SS) return;
    int i = id / SS, j = id - i * SS;
    int n = i - j;
    int ret = (n < 0) ? 16 : 0;
    int na = n < 0 ? -n : n;
    int bucket;
    if (na < 8) {
        bucket = ret + na;
    } else {
        int vil = 8 + (int)(logf((float)na * 0.125f) / logf(16.f) * 8.f);
        vil = vil < 15 ? vil : 15;
        bucket = ret + vil;
    }
    bias[id] = emb[bucket] * 11.313708498984761f;   // sqrt(128)
}

// ---------------- gate-mask: per-batch histogram -> trim ----------------
__global__ __launch_bounds__(256)
void hist_trim_kernel(const float* __restrict__ h, float* __restrict__ trimf) {
    int b = blockIdx.x;
    __shared__ int hist[129];
    __shared__ float wmax[4];
    int t = threadIdx.x;
    if (t < 129) hist[t] = 0;
    __syncthreads();
    float gmax = -1e30f;
    const float* hb = h + (long)b * SS * 1200;
    for (int idx = t; idx < SS * HIDH; idx += 256) {
        int s = idx / HIDH, d = idx - s * HIDH;
        float g = hb[(long)s * 1200 + 600 + d];
        gmax = fmaxf(gmax, g);
        float ag = fabsf(g);
        int bin = (int)fminf(floorf(ag), 128.f);
        atomicAdd(&hist[bin], 1);
    }
    for (int off = 1; off < 64; off <<= 1) gmax = fmaxf(gmax, __shfl_xor(gmax, off));
    if ((t & 63) == 0) wmax[t >> 6] = gmax;
    __syncthreads();
    if (t == 0) {
        float m = fmaxf(fmaxf(wmax[0], wmax[1]), fmaxf(wmax[2], wmax[3]));
        float gmaxf = floorf(m);
        int trim = 1;
        int suffix = 0;
        for (int tt = 128; tt >= 1; --tt) {    // find LARGEST valid t
            suffix += hist[tt];
            if ((float)tt <= gmaxf && suffix > 90000) { trim = tt; break; }
        }
        trimf[b] = (float)trim;
    }
}

// ---------------- gate-mask: 4x4 block counts ----------------
__global__ void counts_kernel(const float* __restrict__ h, const float* __restrict__ trimf,
                              int* __restrict__ counts) {
    int id = blockIdx.x * 256 + threadIdx.x;
    if (id >= BB * 100 * 120) return;
    int b = id / 12000;
    int r = id - b * 12000;
    int bi = r / 120, bj = r - bi * 120;
    float tr = trimf[b];
    const float* hb = h + (long)b * SS * 1200;
    int c = 0;
#pragma unroll
    for (int rr = 0; rr < 4; ++rr)
#pragma unroll
        for (int cc = 0; cc < 4; ++cc) {
            float g = hb[(long)(bi * 5 + rr) * 1200 + 600 + bj * 5 + cc];
            c += (fabsf(g) >= tr) ? 1 : 0;
        }
    counts[id] = c;
}

// ---------------- gate-mask: cmax / c2 -> t2 ----------------
__global__ __launch_bounds__(256)
void t2_kernel(const int* __restrict__ counts, int* __restrict__ t2) {
    int b = blockIdx.x;
    int t = threadIdx.x;
    __shared__ int h2[17];
    __shared__ int smax;
    if (t < 17) h2[t] = 0;
    if (t == 0) smax = 0;
    __syncthreads();
    int lmax = 0;
    for (int i = t; i < 12000; i += 256) {
        int c = counts[b * 12000 + i];
        atomicAdd(&h2[c], 1);
        lmax = lmax > c ? lmax : c;
    }
    atomicMax(&smax, lmax);
    __syncthreads();
    if (t == 0) {
        int cmax = smax;
        int suffix = 0, best = 0;
        bool found = false;
        for (int tt = 16; tt >= 1; --tt) {
            suffix += h2[tt];
            if (!found && tt <= cmax && suffix > 3600) { best = tt; found = true; }
        }
        t2[b] = found ? best : cmax;
    }
}

extern "C" void kernel_launch(void* const* d_in, const int* in_sizes, int n_in,
                              void* d_out, int out_size, void* d_ws, size_t ws_size,
                              hipStream_t stream) {
    const float* x      = (const float*)d_in[0];
    const float* mask2  = (const float*)d_in[1];
    const float* ln_g   = (const float*)d_in[2];
    const float* ln_b   = (const float*)d_in[3];
    const float* Wh     = (const float*)d_in[4];
    const float* bh     = (const float*)d_in[5];
    const float* Wqk    = (const float*)d_in[6];
    const float* bqk    = (const float*)d_in[7];
    const float* gamma  = (const float*)d_in[8];
    const float* beta   = (const float*)d_in[9];
    const float* rel_emb= (const float*)d_in[10];
    const float* Wout   = (const float*)d_in[11];
    const float* bout   = (const float*)d_in[12];
    float* out = (float*)d_out;
    float* ws  = (float*)d_ws;

    // workspace layout (floats)
    float* nx    = ws;                 //  3,000,000
    float* h     = ws + 3000000;       // 12,000,000
    float* qk    = ws + 15000000;      //  1,280,000
    float* q     = ws + 16280000;      //  1,280,000
    float* k     = ws + 17560000;      //  1,280,000
    float* bias  = ws + 18840000;      //    250,000
    float* attn  = ws + 19090000;      //  5,000,000
    float* gated = ws + 24090000;      //  6,000,000
    float* trimf = ws + 30090000;      //         20
    int*   counts= (int*)(ws + 30090020); // 240,000
    int*   t2    = (int*)(ws + 30330020); //      20

    // 1. LayerNorm + shift
    ln_shift_kernel<<<BB * SS, 64, 0, stream>>>(x, ln_g, ln_b, nx);

    // 2. h = silu(nx @ Wh + bh)   (10000 x 1200, K=300)
    gemm_tile<false><<<dim3(19, 157, 1), 256, 0, stream>>>(
        nx, Wh, h, 10000, 1200, 300, 300, 1200, 1200, 0, 0, 0, EpiSiluBias{bh});

    // 3-5. gate mask statistics
    hist_trim_kernel<<<BB, 256, 0, stream>>>(h, trimf);
    counts_kernel<<<(BB * 100 * 120 + 255) / 256, 256, 0, stream>>>(h, trimf, counts);
    t2_kernel<<<BB, 256, 0, stream>>>(counts, t2);

    // 6. qk = silu(nx @ Wqk + bqk)   (10000 x 128, K=300)
    gemm_tile<false><<<dim3(2, 157, 1), 256, 0, stream>>>(
        nx, Wqk, qk, 10000, 128, 300, 300, 128, 128, 0, 0, 0, EpiSiluBias{bqk});

    // 7. rotary -> q, k
    rotary_kernel<<<BB * SS, 128, 0, stream>>>(qk, gamma, beta, q, k);

    // 8. T5 bias table
    t5bias_kernel<<<(SS * SS + 255) / 256, 256, 0, stream>>>(rel_emb, bias);

    // 9. attn = (relu((q k^T + bias)/S))^2 * mask2   (batched, 500x500, K=128)
    gemm_tile<true><<<dim3(8, 8, BB), 256, 0, stream>>>(
        q, k, attn, 500, 500, 128, 128, 128, 500,
        (long)SS * QKD, (long)SS * QKD, (long)SS * SS, EpiAttn{bias, mask2});

    // 10. gated = gm * (attn @ v) * gate   (batched, 500x600, K=500; v = h[:, :600])
    gemm_tile<false><<<dim3(10, 8, BB), 256, 0, stream>>>(
        attn, h, gated, 500, 600, 500, 500, 1200, 600,
        (long)SS * SS, (long)SS * 1200, (long)SS * HIDH, EpiGate{h, counts, t2});

    // 11. out = gated @ Wout + bout + x   (10000 x 300, K=600)
    gemm_tile<false><<<dim3(5, 157, 1), 256, 0, stream>>>(
        gated, Wout, out, 10000, 300, 600, 600, 300, 300, 0, 0, 0, EpiOut{bout, x});
}

// Round 2
// 327.772 us; speedup vs baseline: 2.5439x; 2.5439x over previous
//
#include <hip/hip_runtime.h>
#include <hip/hip_bf16.h>

#define BB 20
#define SS 500
#define DIMD 300
#define HIDH 600
#define QKD 128

typedef unsigned short u16;
typedef __attribute__((ext_vector_type(8))) __bf16 bf16x8;
typedef __attribute__((ext_vector_type(8))) short short8;
typedef __attribute__((ext_vector_type(4))) float floatx4;

__device__ __forceinline__ u16 f2bu(float f) {
    __hip_bfloat16 h = __float2bfloat16(f);
    return *reinterpret_cast<u16*>(&h);
}

__device__ __forceinline__ floatx4 mfma_bf16(short8 a, short8 b, floatx4 c) {
    return __builtin_amdgcn_mfma_f32_16x16x32_bf16(
        __builtin_bit_cast(bf16x8, a), __builtin_bit_cast(bf16x8, b), c, 0, 0, 0);
}

// ---------------- LayerNorm + sequence shift (fp32 nx + padded bf16 nx) ----------------
__global__ __launch_bounds__(64)
void ln_shift_kernel(const float* __restrict__ x, const float* __restrict__ g,
                     const float* __restrict__ be, float* __restrict__ nx,
                     u16* __restrict__ nxb) {
    int bs = blockIdx.x;            // b*500 + s
    int s = bs % SS;
    int t = threadIdx.x;
    const float* xr = x + (long)bs * DIMD;
    float sum = 0.f, sq = 0.f;
    for (int d = t; d < DIMD; d += 64) { float v = xr[d]; sum += v; sq += v * v; }
    for (int off = 1; off < 64; off <<= 1) {
        sum += __shfl_xor(sum, off);
        sq  += __shfl_xor(sq, off);
    }
    float mean = sum * (1.f / DIMD);
    float var  = sq * (1.f / DIMD) - mean * mean;
    float rstd = rsqrtf(var + 1e-5f);
    for (int d = t; d < DIMD; d += 64) {
        float nv = (xr[d] - mean) * rstd * g[d] + be[d];
        if (d < DIMD / 2) {
            if (s < SS - 1) {
                nx[(long)(bs + 1) * DIMD + d] = nv;
                nxb[(long)(bs + 1) * 320 + d] = f2bu(nv);
            }
        } else {
            nx[(long)bs * DIMD + d] = nv;
            nxb[(long)bs * 320 + d] = f2bu(nv);
        }
    }
    if (s == 0)
        for (int d = t; d < DIMD / 2; d += 64) {
            nx[(long)bs * DIMD + d] = 0.f;
            nxb[(long)bs * 320 + d] = 0;
        }
    for (int d = DIMD + t; d < 320; d += 64) nxb[(long)bs * 320 + d] = 0;   // K pad
}

// ---------------- weight convert/transpose to bf16 padded ----------------
__global__ void convert_wh(const float* __restrict__ Wh, u16* __restrict__ WhT) {
    int id = blockIdx.x * 256 + threadIdx.x;   // 1200*320
    if (id >= 1200 * 320) return;
    int n = id / 320, k = id - n * 320;
    float v = (k < 300) ? Wh[(long)k * 1200 + n] : 0.f;
    WhT[id] = f2bu(v);
}
__global__ void convert_wout(const float* __restrict__ Wout, u16* __restrict__ WoutT) {
    int id = blockIdx.x * 256 + threadIdx.x;   // 300*608
    if (id >= 300 * 608) return;
    int n = id / 608, k = id - n * 608;
    float v = (k < 600) ? Wout[(long)k * 300 + n] : 0.f;
    WoutT[id] = f2bu(v);
}

// ---------------- v^T tiled transpose: h[b, k, n<600] -> vT[b][n<640][k<512] bf16 ----------------
__global__ __launch_bounds__(256)
void vT_kernel(const float* __restrict__ h, u16* __restrict__ vT) {
    __shared__ float tile[32][33];
    int b = blockIdx.z;
    int k0 = blockIdx.x * 32;   // sequence index
    int n0 = blockIdx.y * 32;   // hidden index
    int tx = threadIdx.x & 31, ty = threadIdx.x >> 5;
    for (int r = ty; r < 32; r += 8) {
        int k = k0 + r, n = n0 + tx;
        float v = 0.f;
        if (k < SS && n < HIDH) v = h[((long)b * SS + k) * 1200 + n];
        tile[r][tx] = v;
    }
    __syncthreads();
    for (int r = ty; r < 32; r += 8) {
        int n = n0 + r, k = k0 + tx;
        if (n < 640 && k < 512) vT[((long)b * 640 + n) * 512 + k] = f2bu(tile[tx][r]);
    }
}

// ---------------- Epilogues ----------------
struct EpiSiluB {          // h = silu(nx@Wh + bh), fp32 out
    const float* bias; float* hout;
    __device__ void operator()(float acc, int b, int m, int n) const {
        if (m >= 10000 || n >= 1200) return;
        float v = acc + bias[n];
        hout[(long)m * 1200 + n] = v / (1.f + expf(-v));
    }
};
struct EpiSiluQK {         // qk = silu(nx@Wqk + bqk), fp32 out
    const float* bias; float* qkout;
    __device__ void operator()(float acc, int b, int m, int n) const {
        if (m >= 10000 || n >= QKD) return;
        float v = acc + bias[n];
        qkout[(long)m * QKD + n] = v / (1.f + expf(-v));
    }
};
struct EpiAttnB {          // attn = (relu((qk^T+bias)/S))^2 * mask -> bf16 padded [500][512]
    const float* bias; const float* mask; u16* attnb;
    __device__ void operator()(float acc, int b, int m, int n) const {
        if (m >= SS || n >= 512) return;
        float r = 0.f;
        if (n < SS) {
            float s = (acc + bias[m * SS + n]) * (1.f / (float)SS);
            s = fmaxf(s, 0.f);
            r = s * s * mask[m * SS + n];
        }
        attnb[((long)b * SS + m) * 512 + n] = f2bu(r);
    }
};
struct EpiGateB {          // gated = gm * (attn@v) * gate -> bf16 padded [10000][608]
    const float* h; const int* counts; const int* t2v; u16* gated;
    __device__ void operator()(float acc, int b, int m, int n) const {
        if (m >= SS || n >= 608) return;
        float r = 0.f;
        if (n < HIDH) {
            float g = h[((long)(b * SS + m)) * 1200 + 600 + n];
            int c = counts[(b * 100 + m / 5) * 120 + n / 5];
            float bv = (c >= t2v[b]) ? 1.f : 0.25f;
            float p = ((m % 5) == 4 || (n % 5) == 4) ? 0.f : 1.f;
            r = acc * g * bv * p;
        }
        gated[((long)(b * SS + m)) * 608 + n] = f2bu(r);
    }
};
struct EpiOutB {           // out = gated@Wout + bout + x, fp32 out
    const float* bout; const float* x; float* out;
    __device__ void operator()(float acc, int b, int m, int n) const {
        if (m >= 10000 || n >= DIMD) return;
        out[(long)m * DIMD + n] = acc + bout[n] + x[(long)m * DIMD + n];
    }
};

// ---------------- bf16 MFMA GEMM: C[M,N] = A[M,Kp] * Bt[N,Kp]^T ----------------
// A: bf16 [M][lda] row-major, K zero-padded to Kp. Bt: bf16 [Nb][ldb] = B^T, zero-padded.
// 64x64 block tile, 4 waves of 32x32, 16x16x32 MFMA.
template<class Epi>
__global__ __launch_bounds__(256)
void gemm_bf16(const u16* __restrict__ A, const u16* __restrict__ Bt,
               int M, int Nb, int Kp, int lda, int ldb,
               long sA, long sB, Epi epi) {
    int bz = blockIdx.z;
    A += (long)bz * sA; Bt += (long)bz * sB;
    int m0 = blockIdx.y << 6, n0 = blockIdx.x << 6;
    int t = threadIdx.x;
    int lane = t & 63;
    int wm = ((t >> 7) & 1) << 5;
    int wn = ((t >> 6) & 1) << 5;
    int l15 = lane & 15, l4 = lane >> 4;

    __shared__ __align__(16) u16 As[64][40];   // [m][k], +8 pad (80B rows: 2-way-free banks)
    __shared__ __align__(16) u16 Bs[64][40];   // [n][k]

    floatx4 acc00 = {0,0,0,0}, acc01 = {0,0,0,0}, acc10 = {0,0,0,0}, acc11 = {0,0,0,0};

    int srow = t >> 2, skb = (t & 3) << 3;
    const u16* aptr = A + (long)(m0 + srow) * lda + skb;
    const u16* bptr = Bt + (long)(n0 + srow) * ldb + skb;
    bool aval = (m0 + srow) < M;
    bool bval = (n0 + srow) < Nb;

    for (int k0 = 0; k0 < Kp; k0 += 32) {
        int4 av = make_int4(0, 0, 0, 0), bv = make_int4(0, 0, 0, 0);
        if (aval) av = *(const int4*)(aptr + k0);
        if (bval) bv = *(const int4*)(bptr + k0);
        *(int4*)(&As[srow][skb]) = av;
        *(int4*)(&Bs[srow][skb]) = bv;
        __syncthreads();
        short8 a0 = *(const short8*)(&As[wm + l15][l4 << 3]);
        short8 a1 = *(const short8*)(&As[wm + 16 + l15][l4 << 3]);
        short8 b0 = *(const short8*)(&Bs[wn + l15][l4 << 3]);
        short8 b1 = *(const short8*)(&Bs[wn + 16 + l15][l4 << 3]);
        acc00 = mfma_bf16(a0, b0, acc00);
        acc01 = mfma_bf16(a0, b1, acc01);
        acc10 = mfma_bf16(a1, b0, acc10);
        acc11 = mfma_bf16(a1, b1, acc11);
        __syncthreads();
    }
    int bm = m0 + wm + (l4 << 2);
    int bn = n0 + wn + l15;
#pragma unroll
    for (int r = 0; r < 4; ++r) {
        epi(acc00[r], bz, bm + r, bn);
        epi(acc01[r], bz, bm + r, bn + 16);
        epi(acc10[r], bz, bm + 16 + r, bn);
        epi(acc11[r], bz, bm + 16 + r, bn + 16);
    }
}

// ---------------- fp32 tiled GEMM (kept for qk + scores) ----------------
template<bool TRANSB, class Epi>
__global__ __launch_bounds__(256)
void gemm_tile(const float* __restrict__ A, const float* __restrict__ B,
               int M, int N, int K, int lda, int ldb,
               long sA, long sB, Epi epi) {
    int bz = blockIdx.z;
    A += (long)bz * sA; B += (long)bz * sB;
    int m0 = blockIdx.y * 64;
    int n0 = blockIdx.x * 64;
    int t = threadIdx.x;
    int tx = t & 15, ty = t >> 4;

    __shared__ float As[16][68];
    __shared__ float Bs[16][68];

    float acc[4][4] = {};

    for (int k0 = 0; k0 < K; k0 += 16) {
        {
            int row = t >> 2, kb = (t & 3) << 2;
            float4 av = make_float4(0.f, 0.f, 0.f, 0.f);
            if (m0 + row < M && k0 + kb < K)
                av = *(const float4*)(A + (long)(m0 + row) * lda + k0 + kb);
            As[kb + 0][row] = av.x; As[kb + 1][row] = av.y;
            As[kb + 2][row] = av.z; As[kb + 3][row] = av.w;
        }
        if (!TRANSB) {
            int kr = t >> 4, nb = (t & 15) << 2;
            float4 bv = make_float4(0.f, 0.f, 0.f, 0.f);
            if (k0 + kr < K && n0 + nb < N)
                bv = *(const float4*)(B + (long)(k0 + kr) * ldb + n0 + nb);
            *(float4*)(&Bs[kr][nb]) = bv;
        } else {
            int j = t >> 2, kb = (t & 3) << 2;
            float4 bv = make_float4(0.f, 0.f, 0.f, 0.f);
            if (n0 + j < N && k0 + kb < K)
                bv = *(const float4*)(B + (long)(n0 + j) * ldb + k0 + kb);
            Bs[kb + 0][j] = bv.x; Bs[kb + 1][j] = bv.y;
            Bs[kb + 2][j] = bv.z; Bs[kb + 3][j] = bv.w;
        }
        __syncthreads();
#pragma unroll
        for (int kk = 0; kk < 16; ++kk) {
            float4 a = *(const float4*)(&As[kk][ty << 2]);
            float4 bq = *(const float4*)(&Bs[kk][tx << 2]);
            float av4[4] = {a.x, a.y, a.z, a.w};
            float bv4[4] = {bq.x, bq.y, bq.z, bq.w};
#pragma unroll
            for (int i = 0; i < 4; ++i)
#pragma unroll
                for (int j = 0; j < 4; ++j)
                    acc[i][j] = fmaf(av4[i], bv4[j], acc[i][j]);
        }
        __syncthreads();
    }
#pragma unroll
    for (int i = 0; i < 4; ++i)
#pragma unroll
        for (int j = 0; j < 4; ++j)
            epi(acc[i][j], bz, m0 + (ty << 2) + i, n0 + (tx << 2) + j);
}

// ---------------- rotary ----------------
__global__ __launch_bounds__(128)
void rotary_kernel(const float* __restrict__ qk, const float* __restrict__ gamma,
                   const float* __restrict__ beta, float* __restrict__ q,
                   float* __restrict__ k) {
    int bs = blockIdx.x;
    int s = bs % SS;
    int d = threadIdx.x;
    float v = qk[(long)bs * QKD + d];
    float qp = v * gamma[d] + beta[d];
    float kp = v * gamma[QKD + d] + beta[QKD + d];
    float qpart = __shfl_xor(qp, 1);
    float kpart = __shfl_xor(kp, 1);
    float qo = qp, ko = kp;
    if (d < 32) {
        float inv = expf(-(float)(d & ~1) * (logf(10000.f) / 32.f));
        float ang = (float)s * inv;
        float c = cosf(ang), sn = sinf(ang);
        float qr = (d & 1) ? qpart : -qpart;
        float kr = (d & 1) ? kpart : -kpart;
        qo = qp * c + qr * sn;
        ko = kp * c + kr * sn;
    }
    q[(long)bs * QKD + d] = qo;
    k[(long)bs * QKD + d] = ko;
}

// ---------------- T5 bias table ----------------
__global__ void t5bias_kernel(const float* __restrict__ emb, float* __restrict__ bias) {
    int id = blockIdx.x * 256 + threadIdx.x;
    if (id >= SS * SS) return;
    int i = id / SS, j = id - i * SS;
    int n = i - j;
    int ret = (n < 0) ? 16 : 0;
    int na = n < 0 ? -n : n;
    int bucket;
    if (na < 8) {
        bucket = ret + na;
    } else {
        int vil = 8 + (int)(logf((float)na * 0.125f) / logf(16.f) * 8.f);
        vil = vil < 15 ? vil : 15;
        bucket = ret + vil;
    }
    bias[id] = emb[bucket] * 11.313708498984761f;
}

// ---------------- gate stats: init, histogram (bins>=1 only), trim ----------------
__global__ void init_stats(int* __restrict__ hist, unsigned* __restrict__ gmaxu) {
    int i = blockIdx.x * 256 + threadIdx.x;
    if (i < BB * 129) hist[i] = 0;
    if (i < BB) gmaxu[i] = 0u;
}

__global__ __launch_bounds__(256)
void hist_accum_kernel(const float* __restrict__ h, int* __restrict__ hist,
                       unsigned* __restrict__ gmaxu) {
    int b = blockIdx.y;
    const float* hb = h + (long)b * SS * 1200;
    __shared__ int lh[129];
    __shared__ float wmx[4];
    for (int i = threadIdx.x; i < 129; i += 256) lh[i] = 0;
    __syncthreads();
    float lmax = -1e30f;
    int base = blockIdx.x * 2048;
#pragma unroll
    for (int e = 0; e < 8; ++e) {
        int idx = base + e * 256 + threadIdx.x;
        if (idx < SS * HIDH) {
            int s = idx / HIDH, d = idx - s * HIDH;
            float g = hb[(long)s * 1200 + 600 + d];
            lmax = fmaxf(lmax, g);
            float ag = fabsf(g);
            if (ag >= 1.f) {
                int bin = (int)fminf(floorf(ag), 128.f);
                atomicAdd(&lh[bin], 1);
            }
        }
    }
    for (int off = 32; off; off >>= 1) lmax = fmaxf(lmax, __shfl_xor(lmax, off));
    if ((threadIdx.x & 63) == 0) wmx[threadIdx.x >> 6] = lmax;
    __syncthreads();
    if (threadIdx.x == 0) {
        float m = fmaxf(fmaxf(wmx[0], wmx[1]), fmaxf(wmx[2], wmx[3]));
        unsigned bits = __float_as_uint(m);
        unsigned enc = (bits & 0x80000000u) ? ~bits : (bits | 0x80000000u);
        atomicMax(&gmaxu[b], enc);
    }
    for (int i = threadIdx.x; i < 129; i += 256)
        if (lh[i]) atomicAdd(&hist[b * 129 + i], lh[i]);
}

__global__ void trim_kernel(const int* __restrict__ hist, const unsigned* __restrict__ gmaxu,
                            float* __restrict__ trimf) {
    int b = threadIdx.x;
    if (b >= BB) return;
    unsigned enc = gmaxu[b];
    unsigned bits = (enc & 0x80000000u) ? (enc & 0x7FFFFFFFu) : ~enc;
    float gmax = floorf(__uint_as_float(bits));
    int suffix = 0, trim = 1;
    for (int t = 128; t >= 1; --t) {
        suffix += hist[b * 129 + t];
        if ((float)t <= gmax && suffix > 90000) { trim = t; break; }
    }
    trimf[b] = (float)trim;
}

// ---------------- gate-mask: 4x4 block counts ----------------
__global__ void counts_kernel(const float* __restrict__ h, const float* __restrict__ trimf,
                              int* __restrict__ counts) {
    int id = blockIdx.x * 256 + threadIdx.x;
    if (id >= BB * 100 * 120) return;
    int b = id / 12000;
    int r = id - b * 12000;
    int bi = r / 120, bj = r - bi * 120;
    float tr = trimf[b];
    const float* hb = h + (long)b * SS * 1200;
    int c = 0;
#pragma unroll
    for (int rr = 0; rr < 4; ++rr)
#pragma unroll
        for (int cc = 0; cc < 4; ++cc) {
            float g = hb[(long)(bi * 5 + rr) * 1200 + 600 + bj * 5 + cc];
            c += (fabsf(g) >= tr) ? 1 : 0;
        }
    counts[id] = c;
}

// ---------------- t2 (skip c==0 atomics) ----------------
__global__ __launch_bounds__(256)
void t2_kernel(const int* __restrict__ counts, int* __restrict__ t2) {
    int b = blockIdx.x;
    int t = threadIdx.x;
    __shared__ int h2[17];
    __shared__ int smax;
    if (t < 17) h2[t] = 0;
    if (t == 0) smax = 0;
    __syncthreads();
    int lmax = 0;
    for (int i = t; i < 12000; i += 256) {
        int c = counts[b * 12000 + i];
        if (c) atomicAdd(&h2[c], 1);
        lmax = lmax > c ? lmax : c;
    }
    atomicMax(&smax, lmax);
    __syncthreads();
    if (t == 0) {
        int cmax = smax;
        int suffix = 0, best = 0;
        bool found = false;
        for (int tt = 16; tt >= 1; --tt) {
            suffix += h2[tt];
            if (!found && tt <= cmax && suffix > 3600) { best = tt; found = true; }
        }
        t2[b] = found ? best : cmax;
    }
}

extern "C" void kernel_launch(void* const* d_in, const int* in_sizes, int n_in,
                              void* d_out, int out_size, void* d_ws, size_t ws_size,
                              hipStream_t stream) {
    const float* x      = (const float*)d_in[0];
    const float* mask2  = (const float*)d_in[1];
    const float* ln_g   = (const float*)d_in[2];
    const float* ln_b   = (const float*)d_in[3];
    const float* Wh     = (const float*)d_in[4];
    const float* bh     = (const float*)d_in[5];
    const float* Wqk    = (const float*)d_in[6];
    const float* bqk    = (const float*)d_in[7];
    const float* gamma  = (const float*)d_in[8];
    const float* beta   = (const float*)d_in[9];
    const float* rel_emb= (const float*)d_in[10];
    const float* Wout   = (const float*)d_in[11];
    const float* bout   = (const float*)d_in[12];
    float* out = (float*)d_out;
    float* ws  = (float*)d_ws;

    // workspace layout (float offsets)
    float* nx     = ws;                         //  3,000,000
    float* h      = ws + 3000000;               // 12,000,000
    float* qk     = ws + 15000000;              //  1,280,000
    float* q      = ws + 16280000;              //  1,280,000
    float* k      = ws + 17560000;              //  1,280,000
    float* bias   = ws + 18840000;              //    250,000
    u16*   nxb    = (u16*)(ws + 19090000);      //  3,200,000 u16 (10000x320)
    u16*   WhT    = (u16*)(ws + 20690000);      //    384,000 u16 (1200x320)
    u16*   WoutT  = (u16*)(ws + 20882000);      //    182,400 u16 (300x608)
    u16*   attnb  = (u16*)(ws + 20973200);      //  5,120,000 u16 (20x500x512)
    u16*   vT     = (u16*)(ws + 23533200);      //  6,553,600 u16 (20x640x512)
    u16*   gatedb = (u16*)(ws + 26810000);      //  6,080,000 u16 (10000x608)
    float* trimf  = ws + 29850000;              //         20
    int*   hist   = (int*)(ws + 29850020);      //  20x129
    unsigned* gmaxu = (unsigned*)(ws + 29852600); //       20
    int*   counts = (int*)(ws + 29852620);      //    240,000
    int*   t2     = (int*)(ws + 30092620);      //         20

    // 1. LayerNorm + shift (fp32 + padded bf16)
    ln_shift_kernel<<<BB * SS, 64, 0, stream>>>(x, ln_g, ln_b, nx, nxb);

    // 2. weight conversions + stats init
    convert_wh<<<(1200 * 320 + 255) / 256, 256, 0, stream>>>(Wh, WhT);
    convert_wout<<<(300 * 608 + 255) / 256, 256, 0, stream>>>(Wout, WoutT);
    init_stats<<<(BB * 129 + 255) / 256, 256, 0, stream>>>(hist, gmaxu);

    // 3. h = silu(nx @ Wh + bh)  — bf16 MFMA (M=10000, N=1200, Kp=320)
    gemm_bf16<<<dim3(19, 157, 1), 256, 0, stream>>>(
        nxb, WhT, 10000, 1200, 320, 320, 320, 0L, 0L, EpiSiluB{bh, h});

    // 4. gate stats
    hist_accum_kernel<<<dim3(147, BB, 1), 256, 0, stream>>>(h, hist, gmaxu);
    trim_kernel<<<1, 64, 0, stream>>>(hist, gmaxu, trimf);
    counts_kernel<<<(BB * 100 * 120 + 255) / 256, 256, 0, stream>>>(h, trimf, counts);
    t2_kernel<<<BB, 256, 0, stream>>>(counts, t2);

    // 5. qk = silu(nx @ Wqk + bqk)  — fp32
    gemm_tile<false><<<dim3(2, 157, 1), 256, 0, stream>>>(
        nx, Wqk, 10000, 128, 300, 300, 128, 0L, 0L, EpiSiluQK{bqk, qk});

    // 6. rotary
    rotary_kernel<<<BB * SS, 128, 0, stream>>>(qk, gamma, beta, q, k);

    // 7. T5 bias
    t5bias_kernel<<<(SS * SS + 255) / 256, 256, 0, stream>>>(rel_emb, bias);

    // 8. scores -> bf16 attn (padded [500][512])  — fp32 GEMM, B^T layout
    gemm_tile<true><<<dim3(8, 8, BB), 256, 0, stream>>>(
        q, k, 500, 500, 128, 128, 128,
        (long)SS * QKD, (long)SS * QKD, EpiAttnB{bias, mask2, attnb});

    // 9. v^T transpose (bf16, padded, rows 600..639 zeroed)
    vT_kernel<<<dim3(16, 20, BB), 256, 0, stream>>>(h, vT);

    // 10. gated = gm * (attn @ v) * gate  — bf16 MFMA (per batch 500x600, Kp=512)
    gemm_bf16<<<dim3(10, 8, BB), 256, 0, stream>>>(
        attnb, vT, 500, 640, 512, 512, 512,
        (long)500 * 512, (long)640 * 512, EpiGateB{h, counts, t2, gatedb});

    // 11. out = gated @ Wout + bout + x  — bf16 MFMA (M=10000, N=300, Kp=608)
    gemm_bf16<<<dim3(5, 157, 1), 256, 0, stream>>>(
        gatedb, WoutT, 10000, 300, 608, 608, 608, 0L, 0L, EpiOutB{bout, x, out});
}

// Round 3
// 314.295 us; speedup vs baseline: 2.6530x; 1.0429x over previous
//
#include <hip/hip_runtime.h>
#include <hip/hip_bf16.h>

#define BB 20
#define SS 500
#define DIMD 300
#define HIDH 600
#define QKD 128

typedef unsigned short u16;
typedef __attribute__((ext_vector_type(8))) __bf16 bf16x8;
typedef __attribute__((ext_vector_type(8))) short short8;
typedef __attribute__((ext_vector_type(4))) float floatx4;

__device__ __forceinline__ u16 f2bu(float f) {
    __hip_bfloat16 h = __float2bfloat16(f);
    return *reinterpret_cast<u16*>(&h);
}

__device__ __forceinline__ floatx4 mfma_bf16(short8 a, short8 b, floatx4 c) {
    return __builtin_amdgcn_mfma_f32_16x16x32_bf16(
        __builtin_bit_cast(bf16x8, a), __builtin_bit_cast(bf16x8, b), c, 0, 0, 0);
}

// ---------------- LayerNorm + sequence shift -> padded bf16 nxb [10000][320] ----------------
__global__ __launch_bounds__(256)
void ln_shift_kernel(const float* __restrict__ x, const float* __restrict__ g,
                     const float* __restrict__ be, u16* __restrict__ nxb) {
    int bs = blockIdx.x * 4 + (threadIdx.x >> 6);   // 2500 blocks x 4 rows
    int s = bs % SS;
    int t = threadIdx.x & 63;
    const float* xr = x + (long)bs * DIMD;
    float sum = 0.f, sq = 0.f;
    for (int d = t; d < DIMD; d += 64) { float v = xr[d]; sum += v; sq += v * v; }
    for (int off = 1; off < 64; off <<= 1) {
        sum += __shfl_xor(sum, off);
        sq  += __shfl_xor(sq, off);
    }
    float mean = sum * (1.f / DIMD);
    float var  = sq * (1.f / DIMD) - mean * mean;
    float rstd = rsqrtf(var + 1e-5f);
    for (int d = t; d < DIMD; d += 64) {
        float nv = (xr[d] - mean) * rstd * g[d] + be[d];
        if (d < DIMD / 2) {
            if (s < SS - 1) nxb[(long)(bs + 1) * 320 + d] = f2bu(nv);
        } else {
            nxb[(long)bs * 320 + d] = f2bu(nv);
        }
    }
    if (s == 0)
        for (int d = t; d < DIMD / 2; d += 64) nxb[(long)bs * 320 + d] = 0;
    for (int d = DIMD + t; d < 320; d += 64) nxb[(long)bs * 320 + d] = 0;
}

// ---------------- prep: weight transposes + t5 bias + inits + vT pads ----------------
__global__ void prep_kernel(const float* __restrict__ Wh, const float* __restrict__ Wqk,
                            const float* __restrict__ Wout, const float* __restrict__ rel_emb,
                            u16* __restrict__ WhT, u16* __restrict__ Wqkb,
                            u16* __restrict__ WoutT, float* __restrict__ bias,
                            int* __restrict__ hist, unsigned* __restrict__ gmaxu,
                            u16* __restrict__ vT) {
    long id = (long)blockIdx.x * 256 + threadIdx.x;
    if (id < 384000) {                       // WhT[n][k] = Wh[k][n], pad k>=300
        int k = id / 1200, n = id - (long)k * 1200;
        WhT[(long)n * 320 + k] = (k < 300) ? f2bu(Wh[(long)k * 1200 + n]) : (u16)0;
        return;
    }
    id -= 384000;
    if (id < 40960) {                        // Wqkb[n][k]
        int k = id / 128, n = id - (long)k * 128;
        Wqkb[(long)n * 320 + k] = (k < 300) ? f2bu(Wqk[(long)k * 128 + n]) : (u16)0;
        return;
    }
    id -= 40960;
    if (id < 182400) {                       // WoutT[n][k]
        int k = id / 300, n = id - (long)k * 300;
        WoutT[(long)n * 608 + k] = (k < 600) ? f2bu(Wout[(long)k * 300 + n]) : (u16)0;
        return;
    }
    id -= 182400;
    if (id < 250000) {                       // T5 bias table 500x500
        int i = id / 500, j = id - (long)i * 500;
        int n = i - j;
        int ret = (n < 0) ? 16 : 0;
        int na = n < 0 ? -n : n;
        int bucket;
        if (na < 8) bucket = ret + na;
        else {
            int vil = 8 + (int)(logf((float)na * 0.125f) / logf(16.f) * 8.f);
            vil = vil < 15 ? vil : 15;
            bucket = ret + vil;
        }
        bias[id] = rel_emb[bucket] * 11.313708498984761f;
        return;
    }
    id -= 250000;
    if (id < 2580) { hist[id] = 0; return; }
    id -= 2580;
    if (id < 20) { gmaxu[id] = 0u; return; }
    id -= 20;
    if (id < 409600) {                       // vT pad rows m in [600,640)
        int b = id / (40 * 512); int rr = id % (40 * 512);
        int m = 600 + rr / 512, s = rr % 512;
        vT[((long)b * 640 + m) * 512 + s] = 0;
        return;
    }
    id -= 409600;
    if (id < 144000) {                       // vT pad cols s in [500,512)
        int b = id / (600 * 12); int rr = id % (600 * 12);
        int m = rr / 12, s = 500 + rr % 12;
        vT[((long)b * 640 + m) * 512 + s] = 0;
    }
}

// ---------------- Epilogues ----------------
// gemm1 (transposed): m = hidden idx [0,1200), n = token idx [0,10000)
struct EpiH {
    const float* bh; u16* vT; float* gateT;
    __device__ void operator()(float acc, int bz, int m, int n) const {
        if (m >= 1200 || n >= 10000) return;
        float v = acc + bh[m];
        v = v / (1.f + expf(-v));
        int b = n / SS, s = n - b * SS;
        if (m < HIDH) vT[((long)b * 640 + m) * 512 + s] = f2bu(v);
        else gateT[((long)b * HIDH + (m - HIDH)) * SS + s] = v;
    }
};
// qk gemm + fused silu/gamma-beta/rotary; NO early return (shuffles!)
struct EpiQKRot {
    const float* bqk; const float* gamma; const float* beta;
    u16* qb; u16* kb;
    __device__ void operator()(float acc, int bz, int m, int n) const {
        float v = acc + bqk[n];
        v = v / (1.f + expf(-v));
        float qp = v * gamma[n] + beta[n];
        float kp = v * gamma[QKD + n] + beta[QKD + n];
        float qx = __shfl_xor(qp, 1);
        float kx = __shfl_xor(kp, 1);
        float qo = qp, ko = kp;
        if (n < 32) {
            int s = m % SS;
            float inv = expf(-(float)(n & ~1) * (logf(10000.f) / 32.f));
            float ang = (float)s * inv;
            float c, sn;
            sincosf(ang, &sn, &c);
            float qr = (n & 1) ? qx : -qx;
            float kr = (n & 1) ? kx : -kx;
            qo = qp * c + qr * sn;
            ko = kp * c + kr * sn;
        }
        if (m < 10000) {
            qb[(long)m * QKD + n] = f2bu(qo);
            kb[(long)m * QKD + n] = f2bu(ko);
        }
    }
};
struct EpiAttnB {        // scores -> (relu((s+bias)/S))^2 * mask -> bf16 [500][512]
    const float* bias; const float* mask; u16* attnb;
    __device__ void operator()(float acc, int b, int m, int n) const {
        if (m >= SS || n >= 512) return;
        float r = 0.f;
        if (n < SS) {
            float s = (acc + bias[m * SS + n]) * (1.f / (float)SS);
            s = fmaxf(s, 0.f);
            r = s * s * mask[m * SS + n];
        }
        attnb[((long)b * SS + m) * 512 + n] = f2bu(r);
    }
};
struct EpiGateT {        // gated = gm * (attn@v) * gate -> bf16 [10000][608]
    const float* gateT; const int* counts; const int* t2v; u16* gated;
    __device__ void operator()(float acc, int b, int m, int n) const {
        if (m >= SS || n >= 608) return;
        float r = 0.f;
        if (n < HIDH) {
            float g = gateT[((long)b * HIDH + n) * SS + m];
            int c = counts[(b * 100 + m / 5) * 120 + n / 5];
            float bv = (c >= t2v[b]) ? 1.f : 0.25f;
            float p = ((m % 5) == 4 || (n % 5) == 4) ? 0.f : 1.f;
            r = acc * g * bv * p;
        }
        gated[((long)(b * SS + m)) * 608 + n] = f2bu(r);
    }
};
struct EpiOutB {         // out = gated@Wout + bout + x
    const float* bout; const float* x; float* out;
    __device__ void operator()(float acc, int b, int m, int n) const {
        if (m >= 10000 || n >= DIMD) return;
        out[(long)m * DIMD + n] = acc + bout[n] + x[(long)m * DIMD + n];
    }
};

// ---------------- bf16 MFMA GEMM: C[M,N] = A[M,Kp] * Bt[N,Kp]^T ----------------
// BN=64: 4 waves in 2x2, each 32x32. BN=128: 4 waves in 1x4, each 64x32.
template<int BN, class Epi>
__global__ __launch_bounds__(256)
void gemm_bf16(const u16* __restrict__ A, const u16* __restrict__ Bt,
               int M, int Nb, int Kp, int lda, int ldb,
               long sA, long sB, Epi epi) {
    constexpr int NI = (BN == 128) ? 4 : 2;
    int bz = blockIdx.z;
    A += (long)bz * sA; Bt += (long)bz * sB;
    int m0 = blockIdx.y << 6, n0 = blockIdx.x * BN;
    int t = threadIdx.x;
    int lane = t & 63;
    int wave = t >> 6;
    int l15 = lane & 15, l4 = lane >> 4;
    int wm = (BN == 128) ? 0 : ((wave >> 1) << 5);
    int wn = (BN == 128) ? (wave << 5) : ((wave & 1) << 5);

    __shared__ __align__(16) u16 As[64][40];
    __shared__ __align__(16) u16 Bs[BN][40];

    floatx4 acc[NI][2];
#pragma unroll
    for (int i = 0; i < NI; ++i) {
        acc[i][0] = (floatx4){0.f, 0.f, 0.f, 0.f};
        acc[i][1] = (floatx4){0.f, 0.f, 0.f, 0.f};
    }

    int arow = t >> 2, akb = (t & 3) << 3;
    const u16* aptr = A + (long)(m0 + arow) * lda + akb;
    bool aval = (m0 + arow) < M;
    const u16* bptr0 = Bt + (long)(n0 + arow) * ldb + akb;
    bool bval0 = (n0 + arow) < Nb;
    const u16* bptr1 = Bt + (long)(n0 + 64 + arow) * ldb + akb;
    bool bval1 = (n0 + 64 + arow) < Nb;

    for (int k0 = 0; k0 < Kp; k0 += 32) {
        int4 av = make_int4(0, 0, 0, 0), bv0 = make_int4(0, 0, 0, 0), bv1 = make_int4(0, 0, 0, 0);
        if (aval) av = *(const int4*)(aptr + k0);
        if (bval0) bv0 = *(const int4*)(bptr0 + k0);
        if (BN == 128) { if (bval1) bv1 = *(const int4*)(bptr1 + k0); }
        *(int4*)(&As[arow][akb]) = av;
        *(int4*)(&Bs[arow][akb]) = bv0;
        if (BN == 128) *(int4*)(&Bs[64 + arow][akb]) = bv1;
        __syncthreads();
        short8 b0 = *(const short8*)(&Bs[wn + l15][l4 << 3]);
        short8 b1 = *(const short8*)(&Bs[wn + 16 + l15][l4 << 3]);
#pragma unroll
        for (int i = 0; i < NI; ++i) {
            short8 a = *(const short8*)(&As[wm + i * 16 + l15][l4 << 3]);
            acc[i][0] = mfma_bf16(a, b0, acc[i][0]);
            acc[i][1] = mfma_bf16(a, b1, acc[i][1]);
        }
        __syncthreads();
    }
#pragma unroll
    for (int i = 0; i < NI; ++i) {
        int bm = m0 + wm + i * 16 + (l4 << 2);
#pragma unroll
        for (int j = 0; j < 2; ++j) {
            int bn = n0 + wn + j * 16 + l15;
#pragma unroll
            for (int r = 0; r < 4; ++r)
                epi(acc[i][j][r], bz, bm + r, bn);
        }
    }
}

// ---------------- gate stats ----------------
__global__ __launch_bounds__(256)
void hist_accum_kernel(const float* __restrict__ gateT, int* __restrict__ hist,
                       unsigned* __restrict__ gmaxu) {
    int b = blockIdx.y;
    const float* gb = gateT + (long)b * SS * HIDH;
    __shared__ int lh[129];
    __shared__ float wmx[4];
    for (int i = threadIdx.x; i < 129; i += 256) lh[i] = 0;
    __syncthreads();
    float lmax = -1e30f;
    int base = blockIdx.x * 2048;
#pragma unroll
    for (int e = 0; e < 8; ++e) {
        int idx = base + e * 256 + threadIdx.x;
        if (idx < SS * HIDH) {
            float g = gb[idx];
            lmax = fmaxf(lmax, g);
            float ag = fabsf(g);
            if (ag >= 1.f) {
                int bin = (int)fminf(floorf(ag), 128.f);
                atomicAdd(&lh[bin], 1);
            }
        }
    }
    for (int off = 32; off; off >>= 1) lmax = fmaxf(lmax, __shfl_xor(lmax, off));
    if ((threadIdx.x & 63) == 0) wmx[threadIdx.x >> 6] = lmax;
    __syncthreads();
    if (threadIdx.x == 0) {
        float m = fmaxf(fmaxf(wmx[0], wmx[1]), fmaxf(wmx[2], wmx[3]));
        unsigned bits = __float_as_uint(m);
        unsigned enc = (bits & 0x80000000u) ? ~bits : (bits | 0x80000000u);
        atomicMax(&gmaxu[b], enc);
    }
    for (int i = threadIdx.x; i < 129; i += 256)
        if (lh[i]) atomicAdd(&hist[b * 129 + i], lh[i]);
}

__global__ void trim_kernel(const int* __restrict__ hist, const unsigned* __restrict__ gmaxu,
                            float* __restrict__ trimf) {
    int b = threadIdx.x;
    if (b >= BB) return;
    unsigned enc = gmaxu[b];
    unsigned bits = (enc & 0x80000000u) ? (enc & 0x7FFFFFFFu) : ~enc;
    float gmax = floorf(__uint_as_float(bits));
    int suffix = 0, trim = 1;
    for (int t = 128; t >= 1; --t) {
        suffix += hist[b * 129 + t];
        if ((float)t <= gmax && suffix > 90000) { trim = t; break; }
    }
    trimf[b] = (float)trim;
}

__global__ void counts_kernel(const float* __restrict__ gateT, const float* __restrict__ trimf,
                              int* __restrict__ counts) {
    int id = blockIdx.x * 256 + threadIdx.x;
    if (id >= BB * 100 * 120) return;
    int b = id / 12000;
    int r = id - b * 12000;
    int bi = r / 120, bj = r - bi * 120;
    float tr = trimf[b];
    const float* gb = gateT + (long)b * SS * HIDH;
    int c = 0;
#pragma unroll
    for (int cc = 0; cc < 4; ++cc)
#pragma unroll
        for (int rr = 0; rr < 4; ++rr) {
            float g = gb[(long)(bj * 5 + cc) * SS + bi * 5 + rr];
            c += (fabsf(g) >= tr) ? 1 : 0;
        }
    counts[id] = c;
}

__global__ __launch_bounds__(256)
void t2_kernel(const int* __restrict__ counts, int* __restrict__ t2) {
    int b = blockIdx.x;
    int t = threadIdx.x;
    __shared__ int h2[17];
    __shared__ int smax;
    if (t < 17) h2[t] = 0;
    if (t == 0) smax = 0;
    __syncthreads();
    int lmax = 0;
    for (int i = t; i < 12000; i += 256) {
        int c = counts[b * 12000 + i];
        if (c) atomicAdd(&h2[c], 1);
        lmax = lmax > c ? lmax : c;
    }
    atomicMax(&smax, lmax);
    __syncthreads();
    if (t == 0) {
        int cmax = smax;
        int suffix = 0, best = 0;
        bool found = false;
        for (int tt = 16; tt >= 1; --tt) {
            suffix += h2[tt];
            if (!found && tt <= cmax && suffix > 3600) { best = tt; found = true; }
        }
        t2[b] = found ? best : cmax;
    }
}

extern "C" void kernel_launch(void* const* d_in, const int* in_sizes, int n_in,
                              void* d_out, int out_size, void* d_ws, size_t ws_size,
                              hipStream_t stream) {
    const float* x      = (const float*)d_in[0];
    const float* mask2  = (const float*)d_in[1];
    const float* ln_g   = (const float*)d_in[2];
    const float* ln_b   = (const float*)d_in[3];
    const float* Wh     = (const float*)d_in[4];
    const float* bh     = (const float*)d_in[5];
    const float* Wqk    = (const float*)d_in[6];
    const float* bqk    = (const float*)d_in[7];
    const float* gamma  = (const float*)d_in[8];
    const float* beta   = (const float*)d_in[9];
    const float* rel_emb= (const float*)d_in[10];
    const float* Wout   = (const float*)d_in[11];
    const float* bout   = (const float*)d_in[12];
    float* out = (float*)d_out;
    float* ws  = (float*)d_ws;

    // workspace layout (float offsets)
    float* gateT  = ws;                           //  6,000,000 f
    float* bias   = ws + 6000000;                 //    250,000 f
    u16*   nxb    = (u16*)(ws + 6250000);         // 10000x320 u16
    u16*   WhT    = (u16*)(ws + 7850000);         //  1200x320 u16
    u16*   Wqkb   = (u16*)(ws + 8042000);         //   128x320 u16
    u16*   WoutT  = (u16*)(ws + 8062480);         //   300x608 u16
    u16*   qb     = (u16*)(ws + 8153680);         // 10000x128 u16
    u16*   kb     = (u16*)(ws + 8793680);         // 10000x128 u16
    u16*   attnb  = (u16*)(ws + 9433680);         // 20x500x512 u16
    u16*   vT     = (u16*)(ws + 11993680);        // 20x640x512 u16
    u16*   gatedb = (u16*)(ws + 15270480);        // 10000x608 u16
    float* trimf  = ws + 18310480;                //        20
    int*   hist   = (int*)(ws + 18310500);        //    20x129
    unsigned* gmaxu = (unsigned*)(ws + 18313080); //        20
    int*   counts = (int*)(ws + 18313100);        //   240,000
    int*   t2     = (int*)(ws + 18553100);        //        20

    // 1. prep (weights, bias table, inits, vT pads)
    prep_kernel<<<5522, 256, 0, stream>>>(Wh, Wqk, Wout, rel_emb, WhT, Wqkb, WoutT,
                                          bias, hist, gmaxu, vT);
    // 2. LN + shift -> nxb
    ln_shift_kernel<<<2500, 256, 0, stream>>>(x, ln_g, ln_b, nxb);

    // 3. qk gemm + fused silu/rotary -> qb, kb   (M=10000, N=128, Kp=320)
    gemm_bf16<64><<<dim3(2, 157, 1), 256, 0, stream>>>(
        nxb, Wqkb, 10000, QKD, 320, 320, 320, 0L, 0L,
        EpiQKRot{bqk, gamma, beta, qb, kb});

    // 4. gemm1 transposed: C[hid=1200][tok=10000] -> vT (bf16) + gateT (fp32)
    gemm_bf16<128><<<dim3(79, 19, 1), 256, 0, stream>>>(
        WhT, nxb, 1200, 10000, 320, 320, 320, 0L, 0L, EpiH{bh, vT, gateT});

    // 5-8. gate statistics
    hist_accum_kernel<<<dim3(147, BB, 1), 256, 0, stream>>>(gateT, hist, gmaxu);
    trim_kernel<<<1, 64, 0, stream>>>(hist, gmaxu, trimf);
    counts_kernel<<<(BB * 100 * 120 + 255) / 256, 256, 0, stream>>>(gateT, trimf, counts);
    t2_kernel<<<BB, 256, 0, stream>>>(counts, t2);

    // 9. scores: attn = f(q k^T) -> bf16 [b][500][512]   (per batch, Kp=128)
    gemm_bf16<128><<<dim3(4, 8, BB), 256, 0, stream>>>(
        qb, kb, SS, SS, QKD, QKD, QKD,
        (long)SS * QKD, (long)SS * QKD, EpiAttnB{bias, mask2, attnb});

    // 10. attn@v with fused gate mask -> gatedb bf16 [10000][608]  (Kp=512)
    gemm_bf16<128><<<dim3(5, 8, BB), 256, 0, stream>>>(
        attnb, vT, SS, 640, 512, 512, 512,
        (long)SS * 512, (long)640 * 512, EpiGateT{gateT, counts, t2, gatedb});

    // 11. out = gated @ Wout + bout + x   (M=10000, N=300, Kp=608)
    gemm_bf16<64><<<dim3(5, 157, 1), 256, 0, stream>>>(
        gatedb, WoutT, 10000, DIMD, 608, 608, 608, 0L, 0L,
        EpiOutB{bout, x, out});
}

// Round 4
// 303.971 us; speedup vs baseline: 2.7431x; 1.0340x over previous
//
#include <hip/hip_runtime.h>
#include <hip/hip_bf16.h>

#define BB 20
#define SS 500
#define DIMD 300
#define HIDH 600
#define QKD 128

typedef unsigned short u16;
typedef __attribute__((ext_vector_type(8))) __bf16 bf16x8;
typedef __attribute__((ext_vector_type(8))) short short8;
typedef __attribute__((ext_vector_type(4))) float floatx4;

__device__ __forceinline__ u16 f2bu(float f) {
    __hip_bfloat16 h = __float2bfloat16(f);
    return *reinterpret_cast<u16*>(&h);
}

__device__ __forceinline__ floatx4 mfma_bf16(short8 a, short8 b, floatx4 c) {
    return __builtin_amdgcn_mfma_f32_16x16x32_bf16(
        __builtin_bit_cast(bf16x8, a), __builtin_bit_cast(bf16x8, b), c, 0, 0, 0);
}

// async global->LDS, 16B per lane; LDS dest = uniform base + lane*16
__device__ __forceinline__ void glds16(const u16* g, u16* l) {
    __builtin_amdgcn_global_load_lds(
        (__attribute__((address_space(1))) const void*)g,
        (__attribute__((address_space(3))) void*)l, 16, 0, 0);
}

// ---------------- LayerNorm + sequence shift -> padded bf16 nxb [10000][320] ----------------
__global__ __launch_bounds__(256)
void ln_shift_kernel(const float* __restrict__ x, const float* __restrict__ g,
                     const float* __restrict__ be, u16* __restrict__ nxb) {
    int bs = blockIdx.x * 4 + (threadIdx.x >> 6);
    int s = bs % SS;
    int t = threadIdx.x & 63;
    const float* xr = x + (long)bs * DIMD;
    float sum = 0.f, sq = 0.f;
    for (int d = t; d < DIMD; d += 64) { float v = xr[d]; sum += v; sq += v * v; }
    for (int off = 1; off < 64; off <<= 1) {
        sum += __shfl_xor(sum, off);
        sq  += __shfl_xor(sq, off);
    }
    float mean = sum * (1.f / DIMD);
    float var  = sq * (1.f / DIMD) - mean * mean;
    float rstd = rsqrtf(var + 1e-5f);
    for (int d = t; d < DIMD; d += 64) {
        float nv = (xr[d] - mean) * rstd * g[d] + be[d];
        if (d < DIMD / 2) {
            if (s < SS - 1) nxb[(long)(bs + 1) * 320 + d] = f2bu(nv);
        } else {
            nxb[(long)bs * 320 + d] = f2bu(nv);
        }
    }
    if (s == 0)
        for (int d = t; d < DIMD / 2; d += 64) nxb[(long)bs * 320 + d] = 0;
    for (int d = DIMD + t; d < 320; d += 64) nxb[(long)bs * 320 + d] = 0;
}

// ---------------- prep: weight transposes + t5 bias + inits + vT pads ----------------
__global__ void prep_kernel(const float* __restrict__ Wh, const float* __restrict__ Wqk,
                            const float* __restrict__ Wout, const float* __restrict__ rel_emb,
                            u16* __restrict__ WhT, u16* __restrict__ Wqkb,
                            u16* __restrict__ WoutT, float* __restrict__ bias,
                            int* __restrict__ hist, unsigned* __restrict__ gmaxu,
                            u16* __restrict__ vT) {
    long id = (long)blockIdx.x * 256 + threadIdx.x;
    if (id < 384000) {
        int k = id / 1200, n = id - (long)k * 1200;
        WhT[(long)n * 320 + k] = (k < 300) ? f2bu(Wh[(long)k * 1200 + n]) : (u16)0;
        return;
    }
    id -= 384000;
    if (id < 40960) {
        int k = id / 128, n = id - (long)k * 128;
        Wqkb[(long)n * 320 + k] = (k < 300) ? f2bu(Wqk[(long)k * 128 + n]) : (u16)0;
        return;
    }
    id -= 40960;
    if (id < 182400) {
        int k = id / 300, n = id - (long)k * 300;
        WoutT[(long)n * 608 + k] = (k < 600) ? f2bu(Wout[(long)k * 300 + n]) : (u16)0;
        return;
    }
    id -= 182400;
    if (id < 250000) {
        int i = id / 500, j = id - (long)i * 500;
        int n = i - j;
        int ret = (n < 0) ? 16 : 0;
        int na = n < 0 ? -n : n;
        int bucket;
        if (na < 8) bucket = ret + na;
        else {
            int vil = 8 + (int)(logf((float)na * 0.125f) / logf(16.f) * 8.f);
            vil = vil < 15 ? vil : 15;
            bucket = ret + vil;
        }
        bias[id] = rel_emb[bucket] * 11.313708498984761f;
        return;
    }
    id -= 250000;
    if (id < 2580) { hist[id] = 0; return; }
    id -= 2580;
    if (id < 20) { gmaxu[id] = 0u; return; }
    id -= 20;
    if (id < 409600) {
        int b = id / (40 * 512); int rr = id % (40 * 512);
        int m = 600 + rr / 512, s = rr % 512;
        vT[((long)b * 640 + m) * 512 + s] = 0;
        return;
    }
    id -= 409600;
    if (id < 144000) {
        int b = id / (600 * 12); int rr = id % (600 * 12);
        int m = rr / 12, s = 500 + rr % 12;
        vT[((long)b * 640 + m) * 512 + s] = 0;
    }
}

// ---------------- Epilogues ----------------
struct EpiH {            // gemm1 transposed: m = hidden [0,1200), n = token [0,10000)
    const float* bh; u16* vT; float* gateT;
    __device__ void operator()(float acc, int bz, int m, int n) const {
        if (m >= 1200 || n >= 10000) return;
        float v = acc + bh[m];
        v = v / (1.f + expf(-v));
        int b = n / SS, s = n - b * SS;
        if (m < HIDH) vT[((long)b * 640 + m) * 512 + s] = f2bu(v);
        else gateT[((long)b * HIDH + (m - HIDH)) * SS + s] = v;
    }
};
struct EpiQKRot {        // qk + silu + gamma/beta + rotary (NO early return: shuffles)
    const float* bqk; const float* gamma; const float* beta;
    u16* qb; u16* kb;
    __device__ void operator()(float acc, int bz, int m, int n) const {
        float v = acc + bqk[n];
        v = v / (1.f + expf(-v));
        float qp = v * gamma[n] + beta[n];
        float kp = v * gamma[QKD + n] + beta[QKD + n];
        float qx = __shfl_xor(qp, 1);
        float kx = __shfl_xor(kp, 1);
        float qo = qp, ko = kp;
        if (n < 32) {
            int s = m % SS;
            float inv = expf(-(float)(n & ~1) * (logf(10000.f) / 32.f));
            float ang = (float)s * inv;
            float c, sn;
            sincosf(ang, &sn, &c);
            float qr = (n & 1) ? qx : -qx;
            float kr = (n & 1) ? kx : -kx;
            qo = qp * c + qr * sn;
            ko = kp * c + kr * sn;
        }
        if (m < 10000) {
            qb[(long)m * QKD + n] = f2bu(qo);
            kb[(long)m * QKD + n] = f2bu(ko);
        }
    }
};
struct EpiAttnB {        // scores -> (relu((s+bias)/S))^2 * mask -> bf16 [500][512]
    const float* bias; const float* mask; u16* attnb;
    __device__ void operator()(float acc, int b, int m, int n) const {
        if (m >= SS || n >= 512) return;
        float r = 0.f;
        if (n < SS) {
            float s = (acc + bias[m * SS + n]) * (1.f / (float)SS);
            s = fmaxf(s, 0.f);
            r = s * s * mask[m * SS + n];
        }
        attnb[((long)b * SS + m) * 512 + n] = f2bu(r);
    }
};
struct EpiGateT {        // gated = gm * (attn@v) * gate -> bf16 [10000][608]
    const float* gateT; const int* counts; const int* t2v; u16* gated;
    __device__ void operator()(float acc, int b, int m, int n) const {
        if (m >= SS || n >= 608) return;
        float r = 0.f;
        if (n < HIDH) {
            float g = gateT[((long)b * HIDH + n) * SS + m];
            int c = counts[(b * 100 + m / 5) * 120 + n / 5];
            float bv = (c >= t2v[b]) ? 1.f : 0.25f;
            float p = ((m % 5) == 4 || (n % 5) == 4) ? 0.f : 1.f;
            r = acc * g * bv * p;
        }
        gated[((long)(b * SS + m)) * 608 + n] = f2bu(r);
    }
};
struct EpiOutB {         // out = gated@Wout + bout + x
    const float* bout; const float* x; float* out;
    __device__ void operator()(float acc, int b, int m, int n) const {
        if (m >= 10000 || n >= DIMD) return;
        out[(long)m * DIMD + n] = acc + bout[n] + x[(long)m * DIMD + n];
    }
};

// ---------------- bf16 MFMA GEMM, double-buffered global_load_lds staging ----------------
// C[M,N] = A[M,Kp] * Bt[N,Kp]^T.  BK=32.  BN=64: 4 waves 2x2 of 32x32.
// BN=128: 4 waves 1x4, each 64x32.  Staging has NO bounds checks: overrun rows
// read adjacent ws buffers (garbage discarded by epilogue); K-pads are real zeros.
template<int BN, class Epi>
__global__ __launch_bounds__(256)
void gemm_bf16(const u16* __restrict__ A, const u16* __restrict__ Bt,
               int M, int Nb, int Kp, int lda, int ldb,
               long sA, long sB, Epi epi) {
    constexpr int NI = (BN == 128) ? 4 : 2;
    int bz = blockIdx.z;
    A += (long)bz * sA; Bt += (long)bz * sB;
    int m0 = blockIdx.y << 6, n0 = blockIdx.x * BN;
    int t = threadIdx.x;
    int lane = t & 63, wave = t >> 6;
    int l15 = lane & 15, l4 = lane >> 4;
    int wm = (BN == 128) ? 0 : ((wave >> 1) << 5);
    int wn = (BN == 128) ? (wave << 5) : ((wave & 1) << 5);

    __shared__ __align__(16) u16 As[2][64][32];   // unpadded 64B rows (glds contract)
    __shared__ __align__(16) u16 Bs[2][BN][32];

    floatx4 acc[NI][2];
#pragma unroll
    for (int i = 0; i < NI; ++i) {
        acc[i][0] = (floatx4){0.f, 0.f, 0.f, 0.f};
        acc[i][1] = (floatx4){0.f, 0.f, 0.f, 0.f};
    }

    // per-lane global source addresses (wave w stages 16 rows per instr)
    const u16* ag = A + (long)(m0 + (wave << 4) + (lane >> 2)) * lda + ((lane & 3) << 3);
    const u16* bg0;
    const u16* bg1 = nullptr;
    if (BN == 128) {
        bg0 = Bt + (long)(n0 + (wave << 5) + (lane >> 2)) * ldb + ((lane & 3) << 3);
        bg1 = bg0 + (long)16 * ldb;
    } else {
        bg0 = Bt + (long)(n0 + (wave << 4) + (lane >> 2)) * ldb + ((lane & 3) << 3);
    }

    // prologue: stage k0=0 into buf 0
    glds16(ag, &As[0][wave << 4][0]);
    if (BN == 128) {
        glds16(bg0, &Bs[0][wave << 5][0]);
        glds16(bg1, &Bs[0][(wave << 5) + 16][0]);
    } else {
        glds16(bg0, &Bs[0][wave << 4][0]);
    }

    for (int k0 = 0; k0 < Kp; k0 += 32) {
        int buf = (k0 >> 5) & 1;
        __syncthreads();                 // compiler drains vmcnt+lgkm -> buf ready
        int kn = k0 + 32;
        if (kn < Kp) {                   // prefetch next tile into back buffer
            int nb = buf ^ 1;
            glds16(ag + kn, &As[nb][wave << 4][0]);
            if (BN == 128) {
                glds16(bg0 + kn, &Bs[nb][wave << 5][0]);
                glds16(bg1 + kn, &Bs[nb][(wave << 5) + 16][0]);
            } else {
                glds16(bg0 + kn, &Bs[nb][wave << 4][0]);
            }
        }
        short8 b0 = *(const short8*)(&Bs[buf][wn + l15][l4 << 3]);
        short8 b1 = *(const short8*)(&Bs[buf][wn + 16 + l15][l4 << 3]);
#pragma unroll
        for (int i = 0; i < NI; ++i) {
            short8 a = *(const short8*)(&As[buf][wm + (i << 4) + l15][l4 << 3]);
            acc[i][0] = mfma_bf16(a, b0, acc[i][0]);
            acc[i][1] = mfma_bf16(a, b1, acc[i][1]);
        }
    }
#pragma unroll
    for (int i = 0; i < NI; ++i) {
        int bm = m0 + wm + (i << 4) + (l4 << 2);
#pragma unroll
        for (int j = 0; j < 2; ++j) {
            int bn = n0 + wn + j * 16 + l15;
#pragma unroll
            for (int r = 0; r < 4; ++r)
                epi(acc[i][j][r], bz, bm + r, bn);
        }
    }
}

// ---------------- gate stats ----------------
__global__ __launch_bounds__(256)
void hist_accum_kernel(const float* __restrict__ gateT, int* __restrict__ hist,
                       unsigned* __restrict__ gmaxu) {
    int b = blockIdx.y;
    const float* gb = gateT + (long)b * SS * HIDH;
    __shared__ int lh[129];
    __shared__ float wmx[4];
    for (int i = threadIdx.x; i < 129; i += 256) lh[i] = 0;
    __syncthreads();
    float lmax = -1e30f;
    int base = blockIdx.x * 2048;
#pragma unroll
    for (int e = 0; e < 8; ++e) {
        int idx = base + e * 256 + threadIdx.x;
        if (idx < SS * HIDH) {
            float g = gb[idx];
            lmax = fmaxf(lmax, g);
            float ag = fabsf(g);
            if (ag >= 1.f) {
                int bin = (int)fminf(floorf(ag), 128.f);
                atomicAdd(&lh[bin], 1);
            }
        }
    }
    for (int off = 32; off; off >>= 1) lmax = fmaxf(lmax, __shfl_xor(lmax, off));
    if ((threadIdx.x & 63) == 0) wmx[threadIdx.x >> 6] = lmax;
    __syncthreads();
    if (threadIdx.x == 0) {
        float m = fmaxf(fmaxf(wmx[0], wmx[1]), fmaxf(wmx[2], wmx[3]));
        unsigned bits = __float_as_uint(m);
        unsigned enc = (bits & 0x80000000u) ? ~bits : (bits | 0x80000000u);
        atomicMax(&gmaxu[b], enc);
    }
    for (int i = threadIdx.x; i < 129; i += 256)
        if (lh[i]) atomicAdd(&hist[b * 129 + i], lh[i]);
}

__global__ void trim_kernel(const int* __restrict__ hist, const unsigned* __restrict__ gmaxu,
                            float* __restrict__ trimf) {
    int b = threadIdx.x;
    if (b >= BB) return;
    unsigned enc = gmaxu[b];
    unsigned bits = (enc & 0x80000000u) ? (enc & 0x7FFFFFFFu) : ~enc;
    float gmax = floorf(__uint_as_float(bits));
    int suffix = 0, trim = 1;
    for (int t = 128; t >= 1; --t) {
        suffix += hist[b * 129 + t];
        if ((float)t <= gmax && suffix > 90000) { trim = t; break; }
    }
    trimf[b] = (float)trim;
}

__global__ void counts_kernel(const float* __restrict__ gateT, const float* __restrict__ trimf,
                              int* __restrict__ counts) {
    int id = blockIdx.x * 256 + threadIdx.x;
    if (id >= BB * 100 * 120) return;
    int b = id / 12000;
    int r = id - b * 12000;
    int bi = r / 120, bj = r - bi * 120;
    float tr = trimf[b];
    const float* gb = gateT + (long)b * SS * HIDH;
    int c = 0;
#pragma unroll
    for (int cc = 0; cc < 4; ++cc)
#pragma unroll
        for (int rr = 0; rr < 4; ++rr) {
            float g = gb[(long)(bj * 5 + cc) * SS + bi * 5 + rr];
            c += (fabsf(g) >= tr) ? 1 : 0;
        }
    counts[id] = c;
}

__global__ __launch_bounds__(256)
void t2_kernel(const int* __restrict__ counts, int* __restrict__ t2) {
    int b = blockIdx.x;
    int t = threadIdx.x;
    __shared__ int h2[17];
    __shared__ int smax;
    if (t < 17) h2[t] = 0;
    if (t == 0) smax = 0;
    __syncthreads();
    int lmax = 0;
    for (int i = t; i < 12000; i += 256) {
        int c = counts[b * 12000 + i];
        if (c) atomicAdd(&h2[c], 1);
        lmax = lmax > c ? lmax : c;
    }
    atomicMax(&smax, lmax);
    __syncthreads();
    if (t == 0) {
        int cmax = smax;
        int suffix = 0, best = 0;
        bool found = false;
        for (int tt = 16; tt >= 1; --tt) {
            suffix += h2[tt];
            if (!found && tt <= cmax && suffix > 3600) { best = tt; found = true; }
        }
        t2[b] = found ? best : cmax;
    }
}

extern "C" void kernel_launch(void* const* d_in, const int* in_sizes, int n_in,
                              void* d_out, int out_size, void* d_ws, size_t ws_size,
                              hipStream_t stream) {
    const float* x      = (const float*)d_in[0];
    const float* mask2  = (const float*)d_in[1];
    const float* ln_g   = (const float*)d_in[2];
    const float* ln_b   = (const float*)d_in[3];
    const float* Wh     = (const float*)d_in[4];
    const float* bh     = (const float*)d_in[5];
    const float* Wqk    = (const float*)d_in[6];
    const float* bqk    = (const float*)d_in[7];
    const float* gamma  = (const float*)d_in[8];
    const float* beta   = (const float*)d_in[9];
    const float* rel_emb= (const float*)d_in[10];
    const float* Wout   = (const float*)d_in[11];
    const float* bout   = (const float*)d_in[12];
    float* out = (float*)d_out;
    float* ws  = (float*)d_ws;

    // workspace layout (float offsets; all 16B-aligned)
    float* gateT  = ws;                           //  6,000,000 f
    float* bias   = ws + 6000000;                 //    250,000 f
    u16*   nxb    = (u16*)(ws + 6250000);         // 10000x320 u16
    u16*   WhT    = (u16*)(ws + 7850000);         //  1200x320 u16
    u16*   Wqkb   = (u16*)(ws + 8042000);         //   128x320 u16
    u16*   WoutT  = (u16*)(ws + 8062480);         //   300x608 u16
    u16*   qb     = (u16*)(ws + 8153680);         // 10000x128 u16
    u16*   kb     = (u16*)(ws + 8793680);         // 10000x128 u16
    u16*   attnb  = (u16*)(ws + 9433680);         // 20x500x512 u16
    u16*   vT     = (u16*)(ws + 11993680);        // 20x640x512 u16
    u16*   gatedb = (u16*)(ws + 15270480);        // 10000x608 u16
    float* trimf  = ws + 18310480;                //        20
    int*   hist   = (int*)(ws + 18310500);        //    20x129
    unsigned* gmaxu = (unsigned*)(ws + 18313080); //        20
    int*   counts = (int*)(ws + 18313100);        //   240,000
    int*   t2     = (int*)(ws + 18553100);        //        20

    // 1. prep
    prep_kernel<<<5522, 256, 0, stream>>>(Wh, Wqk, Wout, rel_emb, WhT, Wqkb, WoutT,
                                          bias, hist, gmaxu, vT);
    // 2. LN + shift
    ln_shift_kernel<<<2500, 256, 0, stream>>>(x, ln_g, ln_b, nxb);

    // 3. qk gemm + fused silu/rotary -> qb, kb
    gemm_bf16<64><<<dim3(2, 157, 1), 256, 0, stream>>>(
        nxb, Wqkb, 10000, QKD, 320, 320, 320, 0L, 0L,
        EpiQKRot{bqk, gamma, beta, qb, kb});

    // 4. gemm1 transposed -> vT (bf16) + gateT (fp32)
    gemm_bf16<128><<<dim3(79, 19, 1), 256, 0, stream>>>(
        WhT, nxb, 1200, 10000, 320, 320, 320, 0L, 0L, EpiH{bh, vT, gateT});

    // 5-8. gate statistics
    hist_accum_kernel<<<dim3(147, BB, 1), 256, 0, stream>>>(gateT, hist, gmaxu);
    trim_kernel<<<1, 64, 0, stream>>>(hist, gmaxu, trimf);
    counts_kernel<<<(BB * 100 * 120 + 255) / 256, 256, 0, stream>>>(gateT, trimf, counts);
    t2_kernel<<<BB, 256, 0, stream>>>(counts, t2);

    // 9. scores -> attnb bf16 (BN=64: 1280 blocks for occupancy)
    gemm_bf16<64><<<dim3(8, 8, BB), 256, 0, stream>>>(
        qb, kb, SS, SS, QKD, QKD, QKD,
        (long)SS * QKD, (long)SS * QKD, EpiAttnB{bias, mask2, attnb});

    // 10. attn@v + fused gate mask -> gatedb (BN=64: 1600 blocks)
    gemm_bf16<64><<<dim3(10, 8, BB), 256, 0, stream>>>(
        attnb, vT, SS, 640, 512, 512, 512,
        (long)SS * 512, (long)640 * 512, EpiGateT{gateT, counts, t2, gatedb});

    // 11. out = gated @ Wout + bout + x
    gemm_bf16<64><<<dim3(5, 157, 1), 256, 0, stream>>>(
        gatedb, WoutT, 10000, DIMD, 608, 608, 608, 0L, 0L,
        EpiOutB{bout, x, out});
}

// Round 5
// 299.186 us; speedup vs baseline: 2.7870x; 1.0160x over previous
//
#include <hip/hip_runtime.h>
#include <hip/hip_bf16.h>

#define BB 20
#define SS 500
#define DIMD 300
#define HIDH 600
#define QKD 128

typedef unsigned short u16;
typedef __attribute__((ext_vector_type(8))) __bf16 bf16x8;
typedef __attribute__((ext_vector_type(8))) short short8;
typedef __attribute__((ext_vector_type(4))) float floatx4;

__device__ __forceinline__ u16 f2bu(float f) {
    __hip_bfloat16 h = __float2bfloat16(f);
    return *reinterpret_cast<u16*>(&h);
}

__device__ __forceinline__ floatx4 mfma_bf16(short8 a, short8 b, floatx4 c) {
    return __builtin_amdgcn_mfma_f32_16x16x32_bf16(
        __builtin_bit_cast(bf16x8, a), __builtin_bit_cast(bf16x8, b), c, 0, 0, 0);
}

// async global->LDS, 16B per lane; LDS dest = uniform base + lane*16
__device__ __forceinline__ void glds16(const u16* g, u16* l) {
    __builtin_amdgcn_global_load_lds(
        (__attribute__((address_space(1))) const void*)g,
        (__attribute__((address_space(3))) void*)l, 16, 0, 0);
}

// ---------------- LayerNorm + sequence shift -> padded bf16 nxb [10000][320] ----------------
__global__ __launch_bounds__(256)
void ln_shift_kernel(const float* __restrict__ x, const float* __restrict__ g,
                     const float* __restrict__ be, u16* __restrict__ nxb) {
    int bs = blockIdx.x * 4 + (threadIdx.x >> 6);
    int s = bs % SS;
    int t = threadIdx.x & 63;
    const float* xr = x + (long)bs * DIMD;
    float sum = 0.f, sq = 0.f;
    for (int d = t; d < DIMD; d += 64) { float v = xr[d]; sum += v; sq += v * v; }
    for (int off = 1; off < 64; off <<= 1) {
        sum += __shfl_xor(sum, off);
        sq  += __shfl_xor(sq, off);
    }
    float mean = sum * (1.f / DIMD);
    float var  = sq * (1.f / DIMD) - mean * mean;
    float rstd = rsqrtf(var + 1e-5f);
    for (int d = t; d < DIMD; d += 64) {
        float nv = (xr[d] - mean) * rstd * g[d] + be[d];
        if (d < DIMD / 2) {
            if (s < SS - 1) nxb[(long)(bs + 1) * 320 + d] = f2bu(nv);
        } else {
            nxb[(long)bs * 320 + d] = f2bu(nv);
        }
    }
    if (s == 0)
        for (int d = t; d < DIMD / 2; d += 64) nxb[(long)bs * 320 + d] = 0;
    for (int d = DIMD + t; d < 320; d += 64) nxb[(long)bs * 320 + d] = 0;
}

// ---------------- prep: weight transposes + t5 bias + inits + vT pads ----------------
__global__ void prep_kernel(const float* __restrict__ Wh, const float* __restrict__ Wqk,
                            const float* __restrict__ Wout, const float* __restrict__ rel_emb,
                            u16* __restrict__ WhT, u16* __restrict__ Wqkb,
                            u16* __restrict__ WoutT, float* __restrict__ bias,
                            int* __restrict__ hist, unsigned* __restrict__ gmaxu,
                            u16* __restrict__ vT) {
    long id = (long)blockIdx.x * 256 + threadIdx.x;
    if (id < 384000) {
        int k = id / 1200, n = id - (long)k * 1200;
        WhT[(long)n * 320 + k] = (k < 300) ? f2bu(Wh[(long)k * 1200 + n]) : (u16)0;
        return;
    }
    id -= 384000;
    if (id < 40960) {
        int k = id / 128, n = id - (long)k * 128;
        Wqkb[(long)n * 320 + k] = (k < 300) ? f2bu(Wqk[(long)k * 128 + n]) : (u16)0;
        return;
    }
    id -= 40960;
    if (id < 182400) {
        int k = id / 300, n = id - (long)k * 300;
        WoutT[(long)n * 608 + k] = (k < 600) ? f2bu(Wout[(long)k * 300 + n]) : (u16)0;
        return;
    }
    id -= 182400;
    if (id < 250000) {
        int i = id / 500, j = id - (long)i * 500;
        int n = i - j;
        int ret = (n < 0) ? 16 : 0;
        int na = n < 0 ? -n : n;
        int bucket;
        if (na < 8) bucket = ret + na;
        else {
            int vil = 8 + (int)(logf((float)na * 0.125f) / logf(16.f) * 8.f);
            vil = vil < 15 ? vil : 15;
            bucket = ret + vil;
        }
        bias[id] = rel_emb[bucket] * 11.313708498984761f;
        return;
    }
    id -= 250000;
    if (id < 2580) { hist[id] = 0; return; }
    id -= 2580;
    if (id < 20) { gmaxu[id] = 0u; return; }
    id -= 20;
    if (id < 409600) {
        int b = id / (40 * 512); int rr = id % (40 * 512);
        int m = 600 + rr / 512, s = rr % 512;
        vT[((long)b * 640 + m) * 512 + s] = 0;
        return;
    }
    id -= 409600;
    if (id < 144000) {
        int b = id / (600 * 12); int rr = id % (600 * 12);
        int m = rr / 12, s = 500 + rr % 12;
        vT[((long)b * 640 + m) * 512 + s] = 0;
    }
}

// ---------------- Epilogues ----------------
struct EpiH {            // gemm1 transposed: m = hidden [0,1200), n = token [0,10000)
    const float* bh; u16* vT; float* gateT;
    __device__ void operator()(float acc, int bz, int m, int n) const {
        if (m >= 1200 || n >= 10000) return;
        float v = acc + bh[m];
        v = v / (1.f + expf(-v));
        int b = n / SS, s = n - b * SS;
        if (m < HIDH) vT[((long)b * 640 + m) * 512 + s] = f2bu(v);
        else gateT[((long)b * HIDH + (m - HIDH)) * SS + s] = v;
    }
};
struct EpiQKRot {        // qk + silu + gamma/beta + rotary (NO early return: shuffles)
    const float* bqk; const float* gamma; const float* beta;
    u16* qb; u16* kb;
    __device__ void operator()(float acc, int bz, int m, int n) const {
        float v = acc + bqk[n];
        v = v / (1.f + expf(-v));
        float qp = v * gamma[n] + beta[n];
        float kp = v * gamma[QKD + n] + beta[QKD + n];
        float qx = __shfl_xor(qp, 1);
        float kx = __shfl_xor(kp, 1);
        float qo = qp, ko = kp;
        if (n < 32) {
            int s = m % SS;
            float inv = expf(-(float)(n & ~1) * (logf(10000.f) / 32.f));
            float ang = (float)s * inv;
            float c, sn;
            sincosf(ang, &sn, &c);
            float qr = (n & 1) ? qx : -qx;
            float kr = (n & 1) ? kx : -kx;
            qo = qp * c + qr * sn;
            ko = kp * c + kr * sn;
        }
        if (m < 10000) {
            qb[(long)m * QKD + n] = f2bu(qo);
            kb[(long)m * QKD + n] = f2bu(ko);
        }
    }
};
struct EpiAttnB {        // scores -> (relu((s+bias)/S))^2 * mask -> bf16 [500][512]
    const float* bias; const float* mask; u16* attnb;
    __device__ void operator()(float acc, int b, int m, int n) const {
        if (m >= SS || n >= 512) return;
        float r = 0.f;
        if (n < SS) {
            float s = (acc + bias[m * SS + n]) * (1.f / (float)SS);
            s = fmaxf(s, 0.f);
            r = s * s * mask[m * SS + n];
        }
        attnb[((long)b * SS + m) * 512 + n] = f2bu(r);
    }
};
struct EpiGateN {        // gated = gm * (attn@v) * gate -> bf16 [10000][608]; gateN coalesced
    const float* gateN; const int* counts; const int* t2v; u16* gated;
    __device__ void operator()(float acc, int b, int m, int n) const {
        if (m >= SS || n >= 608) return;
        float r = 0.f;
        if (n < HIDH) {
            float g = gateN[((long)b * SS + m) * HIDH + n];
            int c = counts[(b * 100 + m / 5) * 120 + n / 5];
            float bv = (c >= t2v[b]) ? 1.f : 0.25f;
            float p = ((m % 5) == 4 || (n % 5) == 4) ? 0.f : 1.f;
            r = acc * g * bv * p;
        }
        gated[((long)(b * SS + m)) * 608 + n] = f2bu(r);
    }
};
struct EpiOutB {         // out = gated@Wout + bout + x
    const float* bout; const float* x; float* out;
    __device__ void operator()(float acc, int b, int m, int n) const {
        if (m >= 10000 || n >= DIMD) return;
        out[(long)m * DIMD + n] = acc + bout[n] + x[(long)m * DIMD + n];
    }
};

// ---------------- bf16 MFMA GEMM, 3-stage software pipeline ----------------
// C[M,N] = A[M,Kp] * Bt[N,Kp]^T.  BK=32.  BN=64: 4 waves 2x2 of 32x32.
// BN=128: 4 waves 1x4, each 64x32.  Raw s_barrier + manual s_waitcnt vmcnt(N):
// stage k+2 is issued right after the barrier for tile k, so each stage has
// ~2 full compute phases to land (hipBLASLt-style "vmcnt never 0" pipeline).
// Staging has NO bounds checks: overruns land in adjacent ws buffers and the
// garbage rows are discarded by epilogue guards; K-pads are real zeros.
template<int BN, class Epi>
__global__ __launch_bounds__(256)
void gemm_bf16(const u16* __restrict__ A, const u16* __restrict__ Bt,
               int M, int Nb, int Kp, int lda, int ldb,
               long sA, long sB, Epi epi) {
    constexpr int NI = (BN == 128) ? 4 : 2;
    int bz = blockIdx.z;
    A += (long)bz * sA; Bt += (long)bz * sB;
    int m0 = blockIdx.y << 6, n0 = blockIdx.x * BN;
    int t = threadIdx.x;
    int lane = t & 63, wave = t >> 6;
    int l15 = lane & 15, l4 = lane >> 4;
    int wm = (BN == 128) ? 0 : ((wave >> 1) << 5);
    int wn = (BN == 128) ? (wave << 5) : ((wave & 1) << 5);

    __shared__ __align__(16) u16 As[3][64][32];
    __shared__ __align__(16) u16 Bs[3][BN][32];

    floatx4 acc[NI][2];
#pragma unroll
    for (int i = 0; i < NI; ++i) {
        acc[i][0] = (floatx4){0.f, 0.f, 0.f, 0.f};
        acc[i][1] = (floatx4){0.f, 0.f, 0.f, 0.f};
    }

    const u16* ag = A + (long)(m0 + (wave << 4) + (lane >> 2)) * lda + ((lane & 3) << 3);
    const u16* bg0;
    const u16* bg1 = nullptr;
    if (BN == 128) {
        bg0 = Bt + (long)(n0 + (wave << 5) + (lane >> 2)) * ldb + ((lane & 3) << 3);
        bg1 = bg0 + (long)16 * ldb;
    } else {
        bg0 = Bt + (long)(n0 + (wave << 4) + (lane >> 2)) * ldb + ((lane & 3) << 3);
    }

    auto stage = [&](int k0, int buf) {
        glds16(ag + k0, &As[buf][wave << 4][0]);
        if (BN == 128) {
            glds16(bg0 + k0, &Bs[buf][wave << 5][0]);
            glds16(bg1 + k0, &Bs[buf][(wave << 5) + 16][0]);
        } else {
            glds16(bg0 + k0, &Bs[buf][wave << 4][0]);
        }
    };

    int KT = Kp >> 5;
    stage(0, 0);
    stage(32, 1);
    int cur = 0;
    for (int kt = 0; kt < KT - 1; ++kt) {
        // wait until only the newest stage's loads are outstanding -> tile kt landed
        if (BN == 128) asm volatile("s_waitcnt vmcnt(3)" ::: "memory");
        else           asm volatile("s_waitcnt vmcnt(2)" ::: "memory");
        __builtin_amdgcn_s_barrier();
        int kn = (kt + 2) << 5;
        if (kn < Kp) { int nb = cur + 2; if (nb >= 3) nb -= 3; stage(kn, nb); }
        short8 b0 = *(const short8*)(&Bs[cur][wn + l15][l4 << 3]);
        short8 b1 = *(const short8*)(&Bs[cur][wn + 16 + l15][l4 << 3]);
#pragma unroll
        for (int i = 0; i < NI; ++i) {
            short8 a = *(const short8*)(&As[cur][wm + (i << 4) + l15][l4 << 3]);
            acc[i][0] = mfma_bf16(a, b0, acc[i][0]);
            acc[i][1] = mfma_bf16(a, b1, acc[i][1]);
        }
        ++cur; if (cur == 3) cur = 0;
    }
    {   // peeled last iteration: everything must be in
        asm volatile("s_waitcnt vmcnt(0)" ::: "memory");
        __builtin_amdgcn_s_barrier();
        short8 b0 = *(const short8*)(&Bs[cur][wn + l15][l4 << 3]);
        short8 b1 = *(const short8*)(&Bs[cur][wn + 16 + l15][l4 << 3]);
#pragma unroll
        for (int i = 0; i < NI; ++i) {
            short8 a = *(const short8*)(&As[cur][wm + (i << 4) + l15][l4 << 3]);
            acc[i][0] = mfma_bf16(a, b0, acc[i][0]);
            acc[i][1] = mfma_bf16(a, b1, acc[i][1]);
        }
    }
#pragma unroll
    for (int i = 0; i < NI; ++i) {
        int bm = m0 + wm + (i << 4) + (l4 << 2);
#pragma unroll
        for (int j = 0; j < 2; ++j) {
            int bn = n0 + wn + j * 16 + l15;
#pragma unroll
            for (int r = 0; r < 4; ++r)
                epi(acc[i][j][r], bz, bm + r, bn);
        }
    }
}

// ---------------- gate transpose: gateT[b][h][s] -> gateN[b][s][h] ----------------
__global__ __launch_bounds__(256)
void gate_transpose(const float* __restrict__ gateT, float* __restrict__ gateN) {
    __shared__ float tile[32][33];
    int b = blockIdx.z;
    int h0 = blockIdx.x << 5, s0 = blockIdx.y << 5;
    int tx = threadIdx.x & 31, ty = threadIdx.x >> 5;
    const float* gt = gateT + (long)b * HIDH * SS;
    float* gn = gateN + (long)b * SS * HIDH;
    for (int r = ty; r < 32; r += 8) {
        int hh = h0 + r, ss = s0 + tx;
        if (hh < HIDH && ss < SS) tile[r][tx] = gt[(long)hh * SS + ss];
    }
    __syncthreads();
    for (int r = ty; r < 32; r += 8) {
        int ss = s0 + r, hh = h0 + tx;
        if (ss < SS && hh < HIDH) gn[(long)ss * HIDH + hh] = tile[tx][r];
    }
}

// ---------------- gate stats ----------------
__global__ __launch_bounds__(256)
void hist_accum_kernel(const float* __restrict__ gateT, int* __restrict__ hist,
                       unsigned* __restrict__ gmaxu) {
    int b = blockIdx.y;
    const float* gb = gateT + (long)b * SS * HIDH;
    __shared__ int lh[129];
    __shared__ float wmx[4];
    for (int i = threadIdx.x; i < 129; i += 256) lh[i] = 0;
    __syncthreads();
    float lmax = -1e30f;
    int base = blockIdx.x * 2048;
#pragma unroll
    for (int e = 0; e < 8; ++e) {
        int idx = base + e * 256 + threadIdx.x;
        if (idx < SS * HIDH) {
            float g = gb[idx];
            lmax = fmaxf(lmax, g);
            float ag = fabsf(g);
            if (ag >= 1.f) {
                int bin = (int)fminf(floorf(ag), 128.f);
                atomicAdd(&lh[bin], 1);
            }
        }
    }
    for (int off = 32; off; off >>= 1) lmax = fmaxf(lmax, __shfl_xor(lmax, off));
    if ((threadIdx.x & 63) == 0) wmx[threadIdx.x >> 6] = lmax;
    __syncthreads();
    if (threadIdx.x == 0) {
        float m = fmaxf(fmaxf(wmx[0], wmx[1]), fmaxf(wmx[2], wmx[3]));
        unsigned bits = __float_as_uint(m);
        unsigned enc = (bits & 0x80000000u) ? ~bits : (bits | 0x80000000u);
        atomicMax(&gmaxu[b], enc);
    }
    for (int i = threadIdx.x; i < 129; i += 256)
        if (lh[i]) atomicAdd(&hist[b * 129 + i], lh[i]);
}

// counts with integrated trim computation (per-thread; hist is 129 ints in L2)
__global__ void counts_kernel(const float* __restrict__ gateN, const int* __restrict__ hist,
                              const unsigned* __restrict__ gmaxu, int* __restrict__ counts) {
    int id = blockIdx.x * 256 + threadIdx.x;
    if (id >= BB * 100 * 120) return;
    int b = id / 12000;
    unsigned enc = gmaxu[b];
    unsigned bits = (enc & 0x80000000u) ? (enc & 0x7FFFFFFFu) : ~enc;
    float gmax = floorf(__uint_as_float(bits));
    int suffix = 0, trim = 1;
    for (int tt = 128; tt >= 1; --tt) {
        suffix += hist[b * 129 + tt];
        if ((float)tt <= gmax && suffix > 90000) { trim = tt; break; }
    }
    float tr = (float)trim;
    int r = id - b * 12000;
    int bi = r / 120, bj = r - bi * 120;
    const float* gb = gateN + (long)b * SS * HIDH;
    int c = 0;
#pragma unroll
    for (int rr = 0; rr < 4; ++rr)
#pragma unroll
        for (int cc = 0; cc < 4; ++cc) {
            float g = gb[(long)(bi * 5 + rr) * HIDH + bj * 5 + cc];
            c += (fabsf(g) >= tr) ? 1 : 0;
        }
    counts[id] = c;
}

__global__ __launch_bounds__(256)
void t2_kernel(const int* __restrict__ counts, int* __restrict__ t2) {
    int b = blockIdx.x;
    int t = threadIdx.x;
    __shared__ int h2[17];
    __shared__ int smax;
    if (t < 17) h2[t] = 0;
    if (t == 0) smax = 0;
    __syncthreads();
    int lmax = 0;
    for (int i = t; i < 12000; i += 256) {
        int c = counts[b * 12000 + i];
        if (c) atomicAdd(&h2[c], 1);
        lmax = lmax > c ? lmax : c;
    }
    atomicMax(&smax, lmax);
    __syncthreads();
    if (t == 0) {
        int cmax = smax;
        int suffix = 0, best = 0;
        bool found = false;
        for (int tt = 16; tt >= 1; --tt) {
            suffix += h2[tt];
            if (!found && tt <= cmax && suffix > 3600) { best = tt; found = true; }
        }
        t2[b] = found ? best : cmax;
    }
}

extern "C" void kernel_launch(void* const* d_in, const int* in_sizes, int n_in,
                              void* d_out, int out_size, void* d_ws, size_t ws_size,
                              hipStream_t stream) {
    const float* x      = (const float*)d_in[0];
    const float* mask2  = (const float*)d_in[1];
    const float* ln_g   = (const float*)d_in[2];
    const float* ln_b   = (const float*)d_in[3];
    const float* Wh     = (const float*)d_in[4];
    const float* bh     = (const float*)d_in[5];
    const float* Wqk    = (const float*)d_in[6];
    const float* bqk    = (const float*)d_in[7];
    const float* gamma  = (const float*)d_in[8];
    const float* beta   = (const float*)d_in[9];
    const float* rel_emb= (const float*)d_in[10];
    const float* Wout   = (const float*)d_in[11];
    const float* bout   = (const float*)d_in[12];
    float* out = (float*)d_out;
    float* ws  = (float*)d_ws;

    // workspace layout (float offsets; all 16B-aligned)
    float* gateT  = ws;                            //  6,000,000 f
    float* gateN  = ws + 6000000;                  //  6,000,000 f
    float* bias   = ws + 12000000;                 //    250,000 f
    u16*   nxb    = (u16*)(ws + 12250000);         // 10000x320 u16
    u16*   WhT    = (u16*)(ws + 13850000);         //  1200x320 u16
    u16*   Wqkb   = (u16*)(ws + 14042000);         //   128x320 u16
    u16*   WoutT  = (u16*)(ws + 14062480);         //   300x608 u16
    u16*   qb     = (u16*)(ws + 14153680);         // 10000x128 u16
    u16*   kb     = (u16*)(ws + 14793680);         // 10000x128 u16
    u16*   attnb  = (u16*)(ws + 15433680);         // 20x500x512 u16
    u16*   vT     = (u16*)(ws + 17993680);         // 20x640x512 u16
    u16*   gatedb = (u16*)(ws + 21270480);         // 10000x608 u16
    int*   hist   = (int*)(ws + 24310480);         //    20x129
    unsigned* gmaxu = (unsigned*)(ws + 24313060);  //        20
    int*   counts = (int*)(ws + 24313080);         //   240,000
    int*   t2     = (int*)(ws + 24553080);         //        20

    // 1. prep
    prep_kernel<<<5522, 256, 0, stream>>>(Wh, Wqk, Wout, rel_emb, WhT, Wqkb, WoutT,
                                          bias, hist, gmaxu, vT);
    // 2. LN + shift
    ln_shift_kernel<<<2500, 256, 0, stream>>>(x, ln_g, ln_b, nxb);

    // 3. qk gemm + fused silu/rotary -> qb, kb
    gemm_bf16<64><<<dim3(2, 157, 1), 256, 0, stream>>>(
        nxb, Wqkb, 10000, QKD, 320, 320, 320, 0L, 0L,
        EpiQKRot{bqk, gamma, beta, qb, kb});

    // 4. gemm1 transposed -> vT (bf16) + gateT (fp32)
    gemm_bf16<128><<<dim3(79, 19, 1), 256, 0, stream>>>(
        WhT, nxb, 1200, 10000, 320, 320, 320, 0L, 0L, EpiH{bh, vT, gateT});

    // 5. gate transpose -> gateN [b][s][h]
    gate_transpose<<<dim3(19, 16, BB), 256, 0, stream>>>(gateT, gateN);

    // 6-8. gate statistics
    hist_accum_kernel<<<dim3(147, BB, 1), 256, 0, stream>>>(gateT, hist, gmaxu);
    counts_kernel<<<(BB * 100 * 120 + 255) / 256, 256, 0, stream>>>(gateN, hist, gmaxu, counts);
    t2_kernel<<<BB, 256, 0, stream>>>(counts, t2);

    // 9. scores -> attnb bf16
    gemm_bf16<64><<<dim3(8, 8, BB), 256, 0, stream>>>(
        qb, kb, SS, SS, QKD, QKD, QKD,
        (long)SS * QKD, (long)SS * QKD, EpiAttnB{bias, mask2, attnb});

    // 10. attn@v + fused gate mask -> gatedb
    gemm_bf16<64><<<dim3(10, 8, BB), 256, 0, stream>>>(
        attnb, vT, SS, 640, 512, 512, 512,
        (long)SS * 512, (long)640 * 512, EpiGateN{gateN, counts, t2, gatedb});

    // 11. out = gated @ Wout + bout + x
    gemm_bf16<64><<<dim3(5, 157, 1), 256, 0, stream>>>(
        gatedb, WoutT, 10000, DIMD, 608, 608, 608, 0L, 0L,
        EpiOutB{bout, x, out});
}